// Round 6
// baseline (14215.787 us; speedup 1.0000x reference)
//
#include <hip/hip_runtime.h>
#include <hip/hip_bf16.h>

typedef __hip_bfloat16 bf16;

#define NN 192      // nodes per group
#define NG 8        // groups
#define BB 1536     // batch
#define EHID 256
#define DH 320      // decoder hidden
#define PRED 12

__device__ __forceinline__ float waveSum(float v){
#pragma unroll
  for (int o = 32; o > 0; o >>= 1) v += __shfl_down(v, o);
  return v;
}
__device__ __forceinline__ double waveSumD(double v){
#pragma unroll
  for (int o = 32; o > 0; o >>= 1) v += __shfl_down(v, o);
  return v;
}

__device__ __forceinline__ float blockSum(float v, float* red){
  int lane = threadIdx.x & 63, wid = threadIdx.x >> 6, nw = (int)blockDim.x >> 6;
  float s = waveSum(v);
  __syncthreads();
  if (lane == 0) red[wid] = s;
  __syncthreads();
  if (wid == 0){
    float t = (lane < nw) ? red[lane] : 0.f;
    t = waveSum(t);
    if (lane == 0) red[0] = t;
  }
  __syncthreads();
  return red[0];
}
__device__ __forceinline__ double blockSumD(double v, double* red){
  int lane = threadIdx.x & 63, wid = threadIdx.x >> 6, nw = (int)blockDim.x >> 6;
  double s = waveSumD(v);
  __syncthreads();
  if (lane == 0) red[wid] = s;
  __syncthreads();
  if (wid == 0){
    double t = (lane < nw) ? red[lane] : 0.0;
    t = waveSumD(t);
    if (lane == 0) red[0] = t;
  }
  __syncthreads();
  return red[0];
}

// ---------------- dtype probe + conversion ----------------

__global__ void k_zero_int(int* __restrict__ p, int n){
  int i = blockIdx.x*blockDim.x + threadIdx.x;
  if (i < n) p[i] = 0;
}
__global__ void k_zero_f(float* __restrict__ p, int n){
  int i = blockIdx.x*blockDim.x + threadIdx.x;
  if (i < n) p[i] = 0.f;
}

__global__ void k_probe(const unsigned short* __restrict__ src, int n, int* __restrict__ cnt){
  int tid = blockIdx.x*blockDim.x + threadIdx.x;
  int stride = gridDim.x*blockDim.x;
  int bad = 0;
  for (int j = tid; j < n; j += stride){
    float v = __uint_as_float(((unsigned int)src[j]) << 16);
    if (!(fabsf(v) < 100.f)) bad++;
  }
#pragma unroll
  for (int o = 32; o > 0; o >>= 1) bad += __shfl_down(bad, o);
  if ((threadIdx.x & 63) == 0 && bad > 0) atomicAdd(cnt, bad);
}
__global__ void k_flag(const int* __restrict__ cnt, int* __restrict__ flag){
  *flag = (*cnt > 4096) ? 1 : 0;        // 1 = inputs are fp32, 0 = bf16
}

struct CvtArgs {
  const void* src[20];
  float*      dst[20];
  int         n[20];
};

__global__ void k_convert(CvtArgs a, const int* __restrict__ flag){
  int id = blockIdx.y;
  int n = a.n[id];
  float* d = a.dst[id];
  int t = blockIdx.x*blockDim.x + threadIdx.x;
  int stride = gridDim.x*blockDim.x;
  if (*flag == 0){
    const bf16* s = (const bf16*)a.src[id];
    for (int j = t; j < n; j += stride) d[j] = __bfloat162float(s[j]);
  } else {
    const float* s = (const float*)a.src[id];
    for (int j = t; j < n; j += stride) d[j] = s[j];
  }
}

// ---------------- elementwise / small kernels ----------------

__global__ void k_embed(const float* __restrict__ in, const float* __restrict__ W,
                        const float* __restrict__ b, float* __restrict__ out){
  int r = blockIdx.x, e = threadIdx.x;
  float x = in[r*2], y = in[r*2+1];
  float v = W[e*2]*x + W[e*2+1]*y + b[e];
  out[r*64+e] = v > 0.f ? v : 0.f;
}

__global__ void k_concat(const float* __restrict__ henc, const float* __restrict__ z,
                         float* __restrict__ h){
  int idx = blockIdx.x*blockDim.x + threadIdx.x;
  if (idx >= BB*DH) return;
  int b = idx / DH, j = idx - b*DH;
  h[idx] = (j < EHID) ? henc[b*EHID + j] : z[(b/NN)*64 + (j - EHID)];
}

__global__ void k_copy_f(const float* __restrict__ in, float* __restrict__ dst, int n){
  int i = blockIdx.x*blockDim.x + threadIdx.x;
  if (i < n) dst[i] = in[i];
}

// gates = A1@W1^T + A2@W2^T + b1 + b2 ; M=1536, N,K multiples of 32/64
__global__ __launch_bounds__(256) void k_gates(
    const float* __restrict__ A1, const float* __restrict__ W1, int K1,
    const float* __restrict__ A2, const float* __restrict__ W2, int K2,
    const float* __restrict__ b1, const float* __restrict__ b2,
    float* __restrict__ C, int N){
  __shared__ __align__(16) float As[32][68];
  __shared__ __align__(16) float Ws[32][68];
  int tid = threadIdx.x;
  int tx = tid & 15, ty = tid >> 4;
  int n0 = blockIdx.x * 64, m0 = blockIdx.y * 64;
  float acc[4][4] = {};
  for (int ph = 0; ph < 2; ++ph){
    const float* A = ph ? A2 : A1;
    const float* W = ph ? W2 : W1;
    int K = ph ? K2 : K1;
    for (int k0 = 0; k0 < K; k0 += 32){
      {
        int am = tid >> 2, ak = (tid & 3) * 8;
        const float* srcA = A + (size_t)(m0+am)*K + k0 + ak;
        float4 f0 = *(const float4*)(srcA);
        float4 f1 = *(const float4*)(srcA+4);
        As[ak+0][am]=f0.x; As[ak+1][am]=f0.y; As[ak+2][am]=f0.z; As[ak+3][am]=f0.w;
        As[ak+4][am]=f1.x; As[ak+5][am]=f1.y; As[ak+6][am]=f1.z; As[ak+7][am]=f1.w;
        const float* srcW = W + (size_t)(n0+am)*K + k0 + ak;
        float4 w0 = *(const float4*)(srcW);
        float4 w1 = *(const float4*)(srcW+4);
        Ws[ak+0][am]=w0.x; Ws[ak+1][am]=w0.y; Ws[ak+2][am]=w0.z; Ws[ak+3][am]=w0.w;
        Ws[ak+4][am]=w1.x; Ws[ak+5][am]=w1.y; Ws[ak+6][am]=w1.z; Ws[ak+7][am]=w1.w;
      }
      __syncthreads();
#pragma unroll
      for (int k = 0; k < 32; ++k){
        float4 a0 = *(const float4*)&As[k][ty*4];
        float4 b0 = *(const float4*)&Ws[k][tx*4];
        float av[4] = {a0.x, a0.y, a0.z, a0.w};
        float bv[4] = {b0.x, b0.y, b0.z, b0.w};
#pragma unroll
        for (int i = 0; i < 4; ++i)
#pragma unroll
          for (int j = 0; j < 4; ++j)
            acc[i][j] += av[i]*bv[j];
      }
      __syncthreads();
    }
  }
  float bs[4];
#pragma unroll
  for (int j = 0; j < 4; ++j){
    int col = n0 + tx*4 + j;
    bs[j] = b1[col] + b2[col];
  }
#pragma unroll
  for (int i = 0; i < 4; ++i){
    int row = m0 + ty*4 + i;
    float4 v;
    v.x = acc[i][0] + bs[0]; v.y = acc[i][1] + bs[1];
    v.z = acc[i][2] + bs[2]; v.w = acc[i][3] + bs[3];
    *(float4*)&C[(size_t)row*N + n0 + tx*4] = v;
  }
}

__global__ void k_lstm(const float* __restrict__ gates, float* __restrict__ c,
                       float* __restrict__ h, int H){
  int idx = blockIdx.x*blockDim.x + threadIdx.x;
  if (idx >= BB*H) return;
  int b = idx / H, j = idx - b*H;
  const float* g = gates + (size_t)b*4*H;
  float gi = g[j], gf = g[H+j], gg = g[2*H+j], go = g[3*H+j];
  float si = 1.f/(1.f+expf(-gi));
  float sf = 1.f/(1.f+expf(-gf));
  float so = 1.f/(1.f+expf(-go));
  float cc = sf*c[idx] + si*tanhf(gg);
  c[idx] = cc;
  h[idx] = so*tanhf(cc);
}

// h(1536x320) -> traj(1536x2) fp32 + output slice `step` (fp32 or bf16 per flag)
__global__ void k_outproj(const float* __restrict__ h, const float* __restrict__ W,
                          const float* __restrict__ bo, float* __restrict__ traj,
                          void* __restrict__ outbase, int step, const int* __restrict__ flag){
  int b = blockIdx.x, lane = threadIdx.x;
  const float* hb = h + (size_t)b*DH;
  float a0 = 0.f, a1 = 0.f;
  for (int k = lane; k < DH; k += 64){
    float hv = hb[k];
    a0 += hv*W[k];
    a1 += hv*W[DH+k];
  }
  a0 = waveSum(a0); a1 = waveSum(a1);
  if (lane == 0){
    a0 += bo[0]; a1 += bo[1];
    traj[b*2] = a0; traj[b*2+1] = a1;
    size_t idx = (size_t)step*BB*2 + (size_t)b*2;
    if (*flag == 0){
      bf16* o = (bf16*)outbase;
      o[idx] = __float2bfloat16(a0); o[idx+1] = __float2bfloat16(a1);
    } else {
      float* o = (float*)outbase;
      o[idx] = a0; o[idx+1] = a1;
    }
  }
}

// ---------------- signed-graph kernels (fp64 numeric path) ----------------

__global__ void k_sg_emb(const float* __restrict__ h, const float* __restrict__ Wne,
                         const float* __restrict__ bne, const float* __restrict__ Watt,
                         double* __restrict__ sself, double* __restrict__ sother){
  int node = blockIdx.x, e = threadIdx.x;
  const float* hb = h + (size_t)node*DH;
  double acc = (double)bne[e];
  for (int k = 0; k < DH; ++k) acc += (double)hb[k]*(double)Wne[e*DH+k];
  double po = acc * (double)Watt[e];       // a_other = W_att[0, :64]
  double ps = acc * (double)Watt[64+e];    // a_self  = W_att[0, 64:]
  po = waveSumD(po); ps = waveSumD(ps);
  if (e == 0){ sother[node] = po; sself[node] = ps; }
}

__global__ void k_sg_edgecol(const double* __restrict__ sself, const double* __restrict__ sother,
                             const float* __restrict__ batt, double* __restrict__ edge){
  int g = blockIdx.x, j = threadIdx.x;
  const double* ss = sself + g*NN;
  double bb = (double)batt[0];
  double sj = sother[g*NN + j];
  double m = -1e300;
  for (int i = 0; i < NN; ++i){
    double e = ss[i] + sj + bb; e = e > 0.0 ? e : 0.2*e;
    m = fmax(m, e);
  }
  double sum = 0.0;
  for (int i = 0; i < NN; ++i){
    double e = ss[i] + sj + bb; e = e > 0.0 ? e : 0.2*e;
    sum += exp(e - m);
  }
  double* E = edge + (size_t)g*NN*NN;
  for (int i = 0; i < NN; ++i){
    double e = ss[i] + sj + bb; e = e > 0.0 ? e : 0.2*e;
    E[i*NN + j] = exp(e - m)/sum;
  }
}

__global__ void k_sg_sym(const double* __restrict__ edge, double* __restrict__ esym){
  int idx = blockIdx.x*blockDim.x + threadIdx.x;
  if (idx >= NG*NN*NN) return;
  int g = idx / (NN*NN), r = idx - g*NN*NN;
  int i = r / NN, j = r - i*NN;
  const double* E = edge + (size_t)g*NN*NN;
  esym[idx] = (i <= j) ? E[i*NN + j] : E[j*NN + i];
}

__global__ void k_sg_dsum(const double* __restrict__ esym, double* __restrict__ darr){
  int i = blockIdx.x*blockDim.x + threadIdx.x;
  if (i >= NG*NN) return;
  int g = i / NN, li = i - g*NN;
  const double* E = esym + (size_t)g*NN*NN + (size_t)li*NN;
  double s = 0.0;
  for (int j = 0; j < NN; ++j) s += E[j];
  darr[i] = fmax(s, 1e-300);
}

__global__ void k_sg_lsym(const double* __restrict__ esym, const double* __restrict__ darr,
                          double* __restrict__ L){
  int idx = blockIdx.x*blockDim.x + threadIdx.x;
  if (idx >= NG*NN*NN) return;
  int g = idx / (NN*NN), r = idx - g*NN*NN;
  int i = r / NN, j = r - i*NN;
  double w = esym[idx];
  double lij = (i == j) ? (darr[g*NN+i] - w) : (-w);
  L[idx] = lij / (sqrt(darr[g*NN+i])*sqrt(darr[g*NN+j]));
}

// ONE WAVE PER GROUP: Householder tridiag + Sturm bisection + inverse iteration +
// back-transform + Gram-Schmidt vs v0=sqrt(d). fp64, barrier-free (wave64 lockstep).
__global__ __launch_bounds__(64) void k_sg_eigen(double* __restrict__ Amat,
                                                 const double* __restrict__ darr,
                                                 double* __restrict__ v1out){
  __shared__ double v[NN], p[NN], dd[NN], ee[NN], yv[NN], tau_s[NN];
  __shared__ double lu_dl[NN], lu_d[NN], lu_du[NN], lu_du2[NN];
  __shared__ int    lu_piv[NN];
  int g = blockIdx.x;
  double* A = Amat + (size_t)g*NN*NN;
  int lane = threadIdx.x;

  // ---- tridiagonalization (wave-synchronous, no barriers) ----
  for (int k = 0; k < NN-2; ++k){
    double part = 0.0;
    for (int i = k+1+lane; i < NN; i += 64){
      double x = A[(size_t)i*NN + k];
      v[i] = x;
      if (i > k+1) part += x*x;
    }
    double sigma = __shfl(waveSumD(part), 0);
    double alpha = v[k+1];               // LDS broadcast (written by lane 0 above)
    double beta, tau, scale;
    if (sigma <= 1e-280){ tau = 0.0; beta = alpha; scale = 0.0; }
    else {
      beta = -copysign(sqrt(alpha*alpha + sigma), alpha);
      tau = (beta - alpha)/beta;
      scale = 1.0/(alpha - beta);
    }
    if (lane == 0){
      dd[k] = A[(size_t)k*NN + k];
      ee[k] = beta;
      tau_s[k] = tau;
    }
    if (tau != 0.0){
      for (int i = k+2+lane; i < NN; i += 64){ v[i] *= scale; A[(size_t)i*NN + k] = v[i]; }
      if (lane == 0) v[k+1] = 1.0;
      for (int i = k+1+lane; i < NN; i += 64){
        const double* Ai = A + (size_t)i*NN;
        double s = 0.0;
        for (int j = k+1; j < NN; ++j) s += Ai[j]*v[j];
        p[i] = tau*s;
      }
      double pp = 0.0;
      for (int i = k+1+lane; i < NN; i += 64) pp += v[i]*p[i];
      double vtp = __shfl(waveSumD(pp), 0);
      double Kc = 0.5*tau*vtp;
      for (int i = k+1+lane; i < NN; i += 64) p[i] -= Kc*v[i];
      for (int i = k+1+lane; i < NN; i += 64){
        double vi = v[i], qi = p[i];
        double* Ai = A + (size_t)i*NN;
        for (int j = k+1; j < NN; ++j) Ai[j] -= vi*p[j] + qi*v[j];
      }
    }
  }
  if (lane == 0){
    dd[NN-2] = A[(size_t)(NN-2)*NN + NN-2];
    ee[NN-2] = A[(size_t)(NN-1)*NN + NN-2];
    dd[NN-1] = A[(size_t)(NN-1)*NN + NN-1];
  }

  // ---- bisection for 2nd-smallest eigenvalue (64-lane parallel) ----
  double lam1;
  {
    double mn = 1e300, mx = -1e300;
    for (int i = lane; i < NN; i += 64){
      double r = (i > 0 ? fabs(ee[i-1]) : 0.0) + (i < NN-1 ? fabs(ee[i]) : 0.0);
      mn = fmin(mn, dd[i]-r); mx = fmax(mx, dd[i]+r);
    }
#pragma unroll
    for (int o = 32; o > 0; o >>= 1){
      mn = fmin(mn, __shfl_down(mn, o));
      mx = fmax(mx, __shfl_down(mx, o));
    }
    mn = __shfl(mn, 0); mx = __shfl(mx, 0);
    double lo = mn - 1e-8 - 1e-9*fabs(mn);
    double hi = mx + 1e-8 + 1e-9*fabs(mx);
    for (int it = 0; it < 10; ++it){
      double lam = lo + (hi-lo)*((double)(lane+1)/65.0);
      int cnt = 0;
      double q = dd[0] - lam;
      if (q < 0.0) cnt++;
      for (int i2 = 1; i2 < NN; ++i2){
        double den = q;
        if (fabs(den) < 1e-280) den = (den < 0.0) ? -1e-280 : 1e-280;
        q = dd[i2] - lam - ee[i2-1]*ee[i2-1]/den;
        if (q < 0.0) cnt++;
      }
      unsigned long long bal = __ballot(cnt >= 2);
      if (bal == 0ull){
        lo = lo + (hi-lo)*(64.0/65.0);
      } else {
        int j0 = __ffsll(bal) - 1;
        double nl = lo + (hi-lo)*((double)j0/65.0);
        double nh = lo + (hi-lo)*((double)(j0+1)/65.0);
        lo = nl; hi = nh;
      }
    }
    lam1 = 0.5*(lo+hi);
  }

  // ---- LU (T - lam1 I) with partial pivoting + inverse iteration (lane 0) ----
  if (lane == 0){
    for (int i = 0; i < NN; ++i) lu_d[i] = dd[i] - lam1;
    for (int i = 0; i < NN-1; ++i){ lu_dl[i] = ee[i]; lu_du[i] = ee[i]; }
    for (int i = 0; i < NN-2; ++i) lu_du2[i] = 0.0;
    for (int i = 0; i < NN-1; ++i){
      if (fabs(lu_d[i]) >= fabs(lu_dl[i])){
        double di = lu_d[i];
        if (fabs(di) < 1e-30){ di = (di < 0.0) ? -1e-30 : 1e-30; lu_d[i] = di; }
        double fact = lu_dl[i]/di;
        lu_dl[i] = fact;
        lu_d[i+1] -= fact*lu_du[i];
        lu_piv[i] = 0;
      } else {
        double fact = lu_d[i]/lu_dl[i];
        lu_d[i] = lu_dl[i];
        double tmp = lu_d[i+1];
        lu_d[i+1] = lu_du[i] - fact*tmp;
        if (i < NN-2){ lu_du2[i] = lu_du[i+1]; lu_du[i+1] = -fact*lu_du[i+1]; }
        lu_du[i] = tmp;
        lu_dl[i] = fact;
        lu_piv[i] = 1;
      }
    }
    if (fabs(lu_d[NN-1]) < 1e-30)
      lu_d[NN-1] = (lu_d[NN-1] < 0.0) ? -1e-30 : 1e-30;
    for (int i = 0; i < NN; ++i) yv[i] = 1.0 + 0.001*(double)((i*37)%29);
    for (int round = 0; round < 2; ++round){
      for (int i = 0; i < NN-1; ++i){
        if (lu_piv[i] == 0){
          yv[i+1] -= lu_dl[i]*yv[i];
        } else {
          double t = yv[i]; yv[i] = yv[i+1]; yv[i+1] = t - lu_dl[i]*yv[i];
        }
      }
      double mx1 = 0.0;
      for (int i = 0; i < NN; ++i) mx1 = fmax(mx1, fabs(yv[i]));
      double inv1 = (mx1 > 0.0 && isfinite(mx1)) ? 1.0/mx1 : 1.0;
      for (int i = 0; i < NN; ++i) yv[i] *= inv1;
      yv[NN-1] = yv[NN-1]/lu_d[NN-1];
      yv[NN-2] = (yv[NN-2] - lu_du[NN-2]*yv[NN-1])/lu_d[NN-2];
      for (int i = NN-3; i >= 0; --i)
        yv[i] = (yv[i] - lu_du[i]*yv[i+1] - lu_du2[i]*yv[i+2])/lu_d[i];
      double mxv = 0.0;
      for (int i = 0; i < NN; ++i) mxv = fmax(mxv, fabs(yv[i]));
      double inv = (mxv > 0.0 && isfinite(mxv)) ? 1.0/mxv : 1.0;
      for (int i = 0; i < NN; ++i){
        double val = yv[i]*inv;
        if (!isfinite(val)) val = 0.0;
        yv[i] = val;
      }
    }
  }

  // ---- back-transform: y <- H_0 ... H_{n-3} y (wave-synchronous) ----
  for (int k = NN-3; k >= 0; --k){
    double tau = tau_s[k];
    if (tau != 0.0){
      double part = 0.0;
      for (int i = k+1+lane; i < NN; i += 64){
        double vi = (i == k+1) ? 1.0 : A[(size_t)i*NN + k];
        part += vi*yv[i];
      }
      double dot = __shfl(waveSumD(part), 0);
      double s = tau*dot;
      for (int i = k+1+lane; i < NN; i += 64){
        double vi = (i == k+1) ? 1.0 : A[(size_t)i*NN + k];
        yv[i] -= s*vi;
      }
    }
  }

  // ---- Gram-Schmidt against v0 = sqrt(d) ----
  {
    double pd = 0.0, pn2 = 0.0;
    for (int i = lane; i < NN; i += 64){
      double sd = sqrt(darr[g*NN + i]);
      pd += sd*yv[i];
      pn2 += darr[g*NN + i];
    }
    double dot = __shfl(waveSumD(pd), 0);
    double n2  = __shfl(waveSumD(pn2), 0);
    double coef = dot/fmax(n2, 1e-300);
    for (int i = lane; i < NN; i += 64) yv[i] -= coef*sqrt(darr[g*NN + i]);
  }
  double pn = 0.0;
  for (int i = lane; i < NN; i += 64) pn += yv[i]*yv[i];
  double nrm = sqrt(__shfl(waveSumD(pn), 0));
  double inv = (nrm > 0.0 && isfinite(nrm)) ? 1.0/nrm : 0.0;
  for (int i = lane; i < NN; i += 64){
    double val = yv[i]*inv;
    if (!isfinite(val)) val = 0.0;
    v1out[g*NN + i] = val;
  }
}

// kmeans on row-normalized [sqrt(d)/||.||, v1]  (fp64)
__global__ __launch_bounds__(256) void k_sg_kmeans(const double* __restrict__ darr,
                                                   const double* __restrict__ v1,
                                                   int* __restrict__ labels){
  __shared__ double px[NN], py[NN], cx[96], cy[96];
  __shared__ int lab[NN];
  __shared__ double red[16];
  int g = blockIdx.x, tid = threadIdx.x;
  double part = 0.0;
  for (int i = tid; i < NN; i += 256) part += darr[g*NN + i];
  double sumd = blockSumD(part, red);
  double invn = 1.0/sqrt(fmax(sumd, 1e-300));
  for (int i = tid; i < NN; i += 256){
    double h0 = sqrt(darr[g*NN + i])*invn;
    double h1 = v1[g*NN + i];
    double rn = sqrt(h0*h0 + h1*h1);
    double ax = h0/rn, ay = h1/rn;
    if (!isfinite(ax)) ax = 0.0;
    if (!isfinite(ay)) ay = 0.0;
    px[i] = ax; py[i] = ay;
  }
  __syncthreads();
  if (tid < 96){ cx[tid] = px[tid]; cy[tid] = py[tid]; }
  __syncthreads();
  for (int it = 0; it <= 10; ++it){
    if (tid < NN){
      double bx = px[tid], by = py[tid];
      double best = 1e300; int bi = 0;
      for (int a = 0; a < 96; ++a){
        double dx = bx - cx[a], dy = by - cy[a];
        double d2 = dx*dx + dy*dy;
        if (d2 < best){ best = d2; bi = a; }
      }
      lab[tid] = bi;
    }
    __syncthreads();
    if (it == 10) break;
    if (tid < 96){
      int c = 0; double sx = 0.0, sy = 0.0;
      for (int i = 0; i < NN; ++i){
        if (lab[i] == tid){ c++; sx += px[i]; sy += py[i]; }
      }
      if (c > 0){ cx[tid] = sx/(double)c; cy[tid] = sy/(double)c; }
      else      { cx[tid] = px[tid];      cy[tid] = py[tid]; }
    }
    __syncthreads();
  }
  if (tid < NN) labels[g*NN + tid] = lab[tid];
}

// S = pos_alpha + neg_alpha (fp64 in, fp32 out)
__global__ void k_sg_alpha(const double* __restrict__ esym, const int* __restrict__ labels,
                           float* __restrict__ S){
  __shared__ int lbs[NN];
  int g = blockIdx.x, j = threadIdx.x;
  if (j < NN) lbs[j] = labels[g*NN + j];
  __syncthreads();
  const double* E = esym + (size_t)g*NN*NN;
  const double NEG = -100000000.0;
  int lj = lbs[j];
  double mp = -1e300, mn = -1e300;
  for (int i = 0; i < NN; ++i){
    double w = E[i*NN + j];
    bool sm = (lbs[i] == lj);
    double vp = sm ? w : w*NEG; vp = vp > 0.0 ? vp : 0.2*vp;
    double vn = sm ? w*NEG : w; vn = vn > 0.0 ? vn : 0.2*vn;
    mp = fmax(mp, vp); mn = fmax(mn, vn);
  }
  double sp = 0.0, sn = 0.0;
  for (int i = 0; i < NN; ++i){
    double w = E[i*NN + j];
    bool sm = (lbs[i] == lj);
    double vp = sm ? w : w*NEG; vp = vp > 0.0 ? vp : 0.2*vp;
    double vn = sm ? w*NEG : w; vn = vn > 0.0 ? vn : 0.2*vn;
    sp += exp(vp - mp); sn += exp(vn - mn);
  }
  float* So = S + (size_t)g*NN*NN;
  for (int i = 0; i < NN; ++i){
    double w = E[i*NN + j];
    bool sm = (lbs[i] == lj);
    double vp = sm ? w : w*NEG; vp = vp > 0.0 ? vp : 0.2*vp;
    double vn = sm ? w*NEG : w; vn = vn > 0.0 ? vn : 0.2*vn;
    So[i*NN + j] = (float)(exp(vp - mp)/sp + exp(vn - mn)/sn);
  }
}

// h_out[i,:] = sum_j S[i,j] * relu(h_in[j,:]) per group
__global__ __launch_bounds__(320) void k_sg_feat(const float* __restrict__ S,
                                                 const float* __restrict__ hin,
                                                 float* __restrict__ hout){
  int r = blockIdx.x;
  int g = r / NN, li = r - g*NN;
  int dh = threadIdx.x;
  const float* Srow = S + (size_t)g*NN*NN + (size_t)li*NN;
  const float* hb = hin + (size_t)g*NN*DH;
  float acc = 0.f;
  for (int j = 0; j < NN; ++j){
    float w = Srow[j];
    float x = hb[(size_t)j*DH + dh];
    acc += w*(x > 0.f ? x : 0.f);
  }
  hout[(size_t)r*DH + dh] = acc;
}

// ---------------- host ----------------

extern "C" void kernel_launch(void* const* d_in, const int* in_sizes, int n_in,
                              void* d_out, int out_size, void* d_ws, size_t ws_size,
                              hipStream_t stream){
  (void)n_in; (void)out_size; (void)ws_size;

  // ---- workspace layout (float offsets) ----
  float* ws = (float*)d_ws;
  float* inp   = ws;                       // 98304
  float* gates = ws + 98304;               // 1966080
  float* hA    = ws + 2064384;             // 491520
  float* hB    = ws + 2555904;             // 491520
  float* cD    = ws + 3047424;             // 491520
  float* traj  = ws + 3538944;             // 3072
  double* sself_d  = (double*)(ws + 3542016);  // 3072 f
  double* sother_d = (double*)(ws + 3545088);  // 3072 f
  double* darr_d   = (double*)(ws + 3548160);  // 3072 f
  double* v1_d     = (double*)(ws + 3551232);  // 3072 f
  int*    labels   = (int*)(ws + 3554304);     // 1536
  // fp64 graph matrices overlay the (dead) gates buffer:
  double* edge_d = (double*)gates;             // 589824 f
  double* esym_d = (double*)(gates + 589824);  // 589824 f
  double* A_d    = (double*)(gates + 1179648); // 589824 f
  float*  Smat   = gates;                      // fp32 S reuses edge_d space (dead by then)
  // fp32 parameter arena:
  float* a_traj = ws + 3555840;            // 61440
  float* a_z    = ws + 3617280;            // 512
  float* a_Wemb = ws + 3617792;            // 128
  float* a_bemb = ws + 3617920;            // 64
  float* a_Wihe = ws + 3617984;            // 65536
  float* a_Whhe = ws + 3683520;            // 262144
  float* a_bihe = ws + 3945664;            // 1024
  float* a_bhhe = ws + 3946688;            // 1024
  float* a_Wihd = ws + 3947712;            // 81920
  float* a_Whhd = ws + 4029632;            // 409600
  float* a_bihd = ws + 4439232;            // 1280
  float* a_bhhd = ws + 4440512;            // 1280
  float* a_Wout = ws + 4441792;            // 640
  float* a_bout = ws + 4442432;            // 64
  float* a_Wne  = ws + 4442496;            // 20480
  float* a_bne  = ws + 4462976;            // 64
  float* a_Watt = ws + 4463040;            // 128
  float* a_batt = ws + 4463168;            // 64
  int* cnt  = (int*)(ws + 4463232);
  int* flag = (int*)(ws + 4463233);        // ~17.0 MiB total

  // ---- dtype probe ----
  k_zero_int<<<1, 64, 0, stream>>>(cnt, 2);
  k_probe<<<256, 256, 0, stream>>>((const unsigned short*)d_in[1], in_sizes[1], cnt);
  k_flag<<<1, 1, 0, stream>>>(cnt, flag);

  // ---- convert all float inputs to fp32 (enc h/c straight into hB/cD) ----
  CvtArgs ca;
  float* dsts[20] = { a_traj, hB, cD, a_z, a_Wemb, a_bemb, a_Wihe, a_Whhe, a_bihe,
                      a_bhhe, a_Wihd, a_Whhd, a_bihd, a_bhhd, a_Wout, a_bout,
                      a_Wne, a_bne, a_Watt, a_batt };
  for (int i = 0; i < 20; ++i){
    ca.src[i] = d_in[i];
    ca.dst[i] = dsts[i];
    ca.n[i]   = in_sizes[i];
  }
  k_convert<<<dim3(512, 20), 256, 0, stream>>>(ca, flag);

  // ---- encoder LSTM, 8 steps ----
  for (int t = 0; t < 8; ++t){
    k_embed<<<BB, 64, 0, stream>>>(a_traj + (size_t)t*BB*2, a_Wemb, a_bemb, inp);
    k_gates<<<dim3(1024/64, BB/64), 256, 0, stream>>>(inp, a_Wihe, 64, hB, a_Whhe, EHID,
                                                      a_bihe, a_bhhe, gates, 1024);
    k_lstm<<<(BB*EHID+255)/256, 256, 0, stream>>>(gates, cD, hB, EHID);
  }

  // ---- decoder init ----
  k_concat<<<(BB*DH+255)/256, 256, 0, stream>>>(hB, a_z, hA);
  k_zero_f<<<(BB*DH+255)/256, 256, 0, stream>>>(cD, BB*DH);
  k_copy_f<<<(BB*2+255)/256, 256, 0, stream>>>(a_traj + (size_t)7*BB*2, traj, BB*2);

  float* hcur = hA;
  float* hoth = hB;
  for (int i = 0; i < PRED; ++i){
    k_embed<<<BB, 64, 0, stream>>>(traj, a_Wemb, a_bemb, inp);
    if (i == 4){
      k_sg_emb<<<BB, 64, 0, stream>>>(hcur, a_Wne, a_bne, a_Watt, sself_d, sother_d);
      k_sg_edgecol<<<NG, NN, 0, stream>>>(sself_d, sother_d, a_batt, edge_d);
      k_sg_sym<<<(NG*NN*NN+255)/256, 256, 0, stream>>>(edge_d, esym_d);
      k_sg_dsum<<<(NG*NN+255)/256, 256, 0, stream>>>(esym_d, darr_d);
      k_sg_lsym<<<(NG*NN*NN+255)/256, 256, 0, stream>>>(esym_d, darr_d, A_d);
      k_sg_eigen<<<NG, 64, 0, stream>>>(A_d, darr_d, v1_d);
      k_sg_kmeans<<<NG, 256, 0, stream>>>(darr_d, v1_d, labels);
      k_sg_alpha<<<NG, NN, 0, stream>>>(esym_d, labels, Smat);
      k_sg_feat<<<BB, DH, 0, stream>>>(Smat, hcur, hoth);
      float* tmp = hcur; hcur = hoth; hoth = tmp;
    }
    k_gates<<<dim3((4*DH)/64, BB/64), 256, 0, stream>>>(inp, a_Wihd, 64, hcur, a_Whhd, DH,
                                                        a_bihd, a_bhhd, gates, 4*DH);
    k_lstm<<<(BB*DH+255)/256, 256, 0, stream>>>(gates, cD, hcur, DH);
    k_outproj<<<BB, 64, 0, stream>>>(hcur, a_Wout, a_bout, traj, d_out, i, flag);
  }
}

// Round 7
// 6833.814 us; speedup vs baseline: 2.0802x; 2.0802x over previous
//
#include <hip/hip_runtime.h>
#include <hip/hip_bf16.h>

typedef __hip_bfloat16 bf16;

#define NN 192      // nodes per group
#define NG 8        // groups
#define BB 1536     // batch
#define EHID 256
#define DH 320      // decoder hidden
#define PRED 12

__device__ __forceinline__ float waveSum(float v){
#pragma unroll
  for (int o = 32; o > 0; o >>= 1) v += __shfl_down(v, o);
  return v;
}
__device__ __forceinline__ double waveSumD(double v){
#pragma unroll
  for (int o = 32; o > 0; o >>= 1) v += __shfl_down(v, o);
  return v;
}

__device__ __forceinline__ double blockSumD(double v, double* red){
  int lane = threadIdx.x & 63, wid = threadIdx.x >> 6, nw = (int)blockDim.x >> 6;
  double s = waveSumD(v);
  __syncthreads();
  if (lane == 0) red[wid] = s;
  __syncthreads();
  if (wid == 0){
    double t = (lane < nw) ? red[lane] : 0.0;
    t = waveSumD(t);
    if (lane == 0) red[0] = t;
  }
  __syncthreads();
  return red[0];
}

// ---------------- dtype probe + conversion ----------------

__global__ void k_zero_int(int* __restrict__ p, int n){
  int i = blockIdx.x*blockDim.x + threadIdx.x;
  if (i < n) p[i] = 0;
}
__global__ void k_zero_f(float* __restrict__ p, int n){
  int i = blockIdx.x*blockDim.x + threadIdx.x;
  if (i < n) p[i] = 0.f;
}

__global__ void k_probe(const unsigned short* __restrict__ src, int n, int* __restrict__ cnt){
  int tid = blockIdx.x*blockDim.x + threadIdx.x;
  int stride = gridDim.x*blockDim.x;
  int bad = 0;
  for (int j = tid; j < n; j += stride){
    float v = __uint_as_float(((unsigned int)src[j]) << 16);
    if (!(fabsf(v) < 100.f)) bad++;
  }
#pragma unroll
  for (int o = 32; o > 0; o >>= 1) bad += __shfl_down(bad, o);
  if ((threadIdx.x & 63) == 0 && bad > 0) atomicAdd(cnt, bad);
}
__global__ void k_flag(const int* __restrict__ cnt, int* __restrict__ flag){
  *flag = (*cnt > 4096) ? 1 : 0;        // 1 = inputs are fp32, 0 = bf16
}

struct CvtArgs {
  const void* src[20];
  float*      dst[20];
  int         n[20];
};

__global__ void k_convert(CvtArgs a, const int* __restrict__ flag){
  int id = blockIdx.y;
  int n = a.n[id];
  float* d = a.dst[id];
  int t = blockIdx.x*blockDim.x + threadIdx.x;
  int stride = gridDim.x*blockDim.x;
  if (*flag == 0){
    const bf16* s = (const bf16*)a.src[id];
    for (int j = t; j < n; j += stride) d[j] = __bfloat162float(s[j]);
  } else {
    const float* s = (const float*)a.src[id];
    for (int j = t; j < n; j += stride) d[j] = s[j];
  }
}

// ---------------- elementwise / small kernels ----------------

__global__ void k_embed(const float* __restrict__ in, const float* __restrict__ W,
                        const float* __restrict__ b, float* __restrict__ out){
  int r = blockIdx.x, e = threadIdx.x;
  float x = in[r*2], y = in[r*2+1];
  float v = W[e*2]*x + W[e*2+1]*y + b[e];
  out[r*64+e] = v > 0.f ? v : 0.f;
}

__global__ void k_concat(const float* __restrict__ henc, const float* __restrict__ z,
                         float* __restrict__ h){
  int idx = blockIdx.x*blockDim.x + threadIdx.x;
  if (idx >= BB*DH) return;
  int b = idx / DH, j = idx - b*DH;
  h[idx] = (j < EHID) ? henc[b*EHID + j] : z[(b/NN)*64 + (j - EHID)];
}

__global__ void k_copy_f(const float* __restrict__ in, float* __restrict__ dst, int n){
  int i = blockIdx.x*blockDim.x + threadIdx.x;
  if (i < n) dst[i] = in[i];
}

// gates = A1@W1^T + A2@W2^T + b1 + b2 ; M=1536, N,K multiples of 32/64
__global__ __launch_bounds__(256) void k_gates(
    const float* __restrict__ A1, const float* __restrict__ W1, int K1,
    const float* __restrict__ A2, const float* __restrict__ W2, int K2,
    const float* __restrict__ b1, const float* __restrict__ b2,
    float* __restrict__ C, int N){
  __shared__ __align__(16) float As[32][68];
  __shared__ __align__(16) float Ws[32][68];
  int tid = threadIdx.x;
  int tx = tid & 15, ty = tid >> 4;
  int n0 = blockIdx.x * 64, m0 = blockIdx.y * 64;
  float acc[4][4] = {};
  for (int ph = 0; ph < 2; ++ph){
    const float* A = ph ? A2 : A1;
    const float* W = ph ? W2 : W1;
    int K = ph ? K2 : K1;
    for (int k0 = 0; k0 < K; k0 += 32){
      {
        int am = tid >> 2, ak = (tid & 3) * 8;
        const float* srcA = A + (size_t)(m0+am)*K + k0 + ak;
        float4 f0 = *(const float4*)(srcA);
        float4 f1 = *(const float4*)(srcA+4);
        As[ak+0][am]=f0.x; As[ak+1][am]=f0.y; As[ak+2][am]=f0.z; As[ak+3][am]=f0.w;
        As[ak+4][am]=f1.x; As[ak+5][am]=f1.y; As[ak+6][am]=f1.z; As[ak+7][am]=f1.w;
        const float* srcW = W + (size_t)(n0+am)*K + k0 + ak;
        float4 w0 = *(const float4*)(srcW);
        float4 w1 = *(const float4*)(srcW+4);
        Ws[ak+0][am]=w0.x; Ws[ak+1][am]=w0.y; Ws[ak+2][am]=w0.z; Ws[ak+3][am]=w0.w;
        Ws[ak+4][am]=w1.x; Ws[ak+5][am]=w1.y; Ws[ak+6][am]=w1.z; Ws[ak+7][am]=w1.w;
      }
      __syncthreads();
#pragma unroll
      for (int k = 0; k < 32; ++k){
        float4 a0 = *(const float4*)&As[k][ty*4];
        float4 b0 = *(const float4*)&Ws[k][tx*4];
        float av[4] = {a0.x, a0.y, a0.z, a0.w};
        float bv[4] = {b0.x, b0.y, b0.z, b0.w};
#pragma unroll
        for (int i = 0; i < 4; ++i)
#pragma unroll
          for (int j = 0; j < 4; ++j)
            acc[i][j] += av[i]*bv[j];
      }
      __syncthreads();
    }
  }
  float bs[4];
#pragma unroll
  for (int j = 0; j < 4; ++j){
    int col = n0 + tx*4 + j;
    bs[j] = b1[col] + b2[col];
  }
#pragma unroll
  for (int i = 0; i < 4; ++i){
    int row = m0 + ty*4 + i;
    float4 v;
    v.x = acc[i][0] + bs[0]; v.y = acc[i][1] + bs[1];
    v.z = acc[i][2] + bs[2]; v.w = acc[i][3] + bs[3];
    *(float4*)&C[(size_t)row*N + n0 + tx*4] = v;
  }
}

__global__ void k_lstm(const float* __restrict__ gates, float* __restrict__ c,
                       float* __restrict__ h, int H){
  int idx = blockIdx.x*blockDim.x + threadIdx.x;
  if (idx >= BB*H) return;
  int b = idx / H, j = idx - b*H;
  const float* g = gates + (size_t)b*4*H;
  float gi = g[j], gf = g[H+j], gg = g[2*H+j], go = g[3*H+j];
  float si = 1.f/(1.f+expf(-gi));
  float sf = 1.f/(1.f+expf(-gf));
  float so = 1.f/(1.f+expf(-go));
  float cc = sf*c[idx] + si*tanhf(gg);
  c[idx] = cc;
  h[idx] = so*tanhf(cc);
}

// h(1536x320) -> traj(1536x2) fp32 + output slice `step` (fp32 or bf16 per flag)
__global__ void k_outproj(const float* __restrict__ h, const float* __restrict__ W,
                          const float* __restrict__ bo, float* __restrict__ traj,
                          void* __restrict__ outbase, int step, const int* __restrict__ flag){
  int b = blockIdx.x, lane = threadIdx.x;
  const float* hb = h + (size_t)b*DH;
  float a0 = 0.f, a1 = 0.f;
  for (int k = lane; k < DH; k += 64){
    float hv = hb[k];
    a0 += hv*W[k];
    a1 += hv*W[DH+k];
  }
  a0 = waveSum(a0); a1 = waveSum(a1);
  if (lane == 0){
    a0 += bo[0]; a1 += bo[1];
    traj[b*2] = a0; traj[b*2+1] = a1;
    size_t idx = (size_t)step*BB*2 + (size_t)b*2;
    if (*flag == 0){
      bf16* o = (bf16*)outbase;
      o[idx] = __float2bfloat16(a0); o[idx+1] = __float2bfloat16(a1);
    } else {
      float* o = (float*)outbase;
      o[idx] = a0; o[idx+1] = a1;
    }
  }
}

// ---------------- signed-graph kernels (fp64 numeric path) ----------------

__global__ void k_sg_emb(const float* __restrict__ h, const float* __restrict__ Wne,
                         const float* __restrict__ bne, const float* __restrict__ Watt,
                         double* __restrict__ sself, double* __restrict__ sother){
  int node = blockIdx.x, e = threadIdx.x;
  const float* hb = h + (size_t)node*DH;
  double acc = (double)bne[e];
  for (int k = 0; k < DH; ++k) acc += (double)hb[k]*(double)Wne[e*DH+k];
  double po = acc * (double)Watt[e];       // a_other = W_att[0, :64]
  double ps = acc * (double)Watt[64+e];    // a_self  = W_att[0, 64:]
  po = waveSumD(po); ps = waveSumD(ps);
  if (e == 0){ sother[node] = po; sself[node] = ps; }
}

__global__ void k_sg_edgecol(const double* __restrict__ sself, const double* __restrict__ sother,
                             const float* __restrict__ batt, double* __restrict__ edge){
  int g = blockIdx.x, j = threadIdx.x;
  const double* ss = sself + g*NN;
  double bb = (double)batt[0];
  double sj = sother[g*NN + j];
  double m = -1e300;
  for (int i = 0; i < NN; ++i){
    double e = ss[i] + sj + bb; e = e > 0.0 ? e : 0.2*e;
    m = fmax(m, e);
  }
  double sum = 0.0;
  for (int i = 0; i < NN; ++i){
    double e = ss[i] + sj + bb; e = e > 0.0 ? e : 0.2*e;
    sum += exp(e - m);
  }
  double* E = edge + (size_t)g*NN*NN;
  for (int i = 0; i < NN; ++i){
    double e = ss[i] + sj + bb; e = e > 0.0 ? e : 0.2*e;
    E[i*NN + j] = exp(e - m)/sum;
  }
}

__global__ void k_sg_sym(const double* __restrict__ edge, double* __restrict__ esym){
  int idx = blockIdx.x*blockDim.x + threadIdx.x;
  if (idx >= NG*NN*NN) return;
  int g = idx / (NN*NN), r = idx - g*NN*NN;
  int i = r / NN, j = r - i*NN;
  const double* E = edge + (size_t)g*NN*NN;
  esym[idx] = (i <= j) ? E[i*NN + j] : E[j*NN + i];
}

__global__ void k_sg_dsum(const double* __restrict__ esym, double* __restrict__ darr){
  int i = blockIdx.x*blockDim.x + threadIdx.x;
  if (i >= NG*NN) return;
  int g = i / NN, li = i - g*NN;
  const double* E = esym + (size_t)g*NN*NN + (size_t)li*NN;
  double s = 0.0;
  for (int j = 0; j < NN; ++j) s += E[j];
  darr[i] = fmax(s, 1e-300);
}

__global__ void k_sg_lsym(const double* __restrict__ esym, const double* __restrict__ darr,
                          double* __restrict__ L){
  int idx = blockIdx.x*blockDim.x + threadIdx.x;
  if (idx >= NG*NN*NN) return;
  int g = idx / (NN*NN), r = idx - g*NN*NN;
  int i = r / NN, j = r - i*NN;
  double w = esym[idx];
  double lij = (i == j) ? (darr[g*NN+i] - w) : (-w);
  L[idx] = lij / (sqrt(darr[g*NN+i])*sqrt(darr[g*NN+j]));
}

// 256 THREADS (4 waves) PER GROUP, barrier-lean Householder tridiag + Sturm
// bisection + inverse iteration + back-transform + Gram-Schmidt vs v0=sqrt(d).
// fp64. A destroyed; v1out unit. ~5 barriers/step fwd, 2/step back.
__global__ __launch_bounds__(256) void k_sg_eigen(double* __restrict__ Amat,
                                                  const double* __restrict__ darr,
                                                  double* __restrict__ v1out){
  __shared__ double v[NN], p[NN], dd[NN], ee[NN], yv[NN], tau_s[NN];
  __shared__ double lu_dl[NN], lu_d[NN], lu_du[NN], lu_du2[NN];
  __shared__ int    lu_piv[NN];
  __shared__ double red4[4];
  int g = blockIdx.x;
  double* A = Amat + (size_t)g*NN*NN;
  int tid = threadIdx.x;
  int lane = tid & 63, wid = tid >> 6;   // 4 waves

  // ---- tridiagonalization ----
  for (int k = 0; k < NN-2; ++k){
    // load column k into v, partial sigma over i>k+1
    double part = 0.0;
    for (int i = k+1+tid; i < NN; i += 256){
      double x = A[(size_t)i*NN + k];
      v[i] = x;
      if (i > k+1) part += x*x;
    }
    part = waveSumD(part);
    if (lane == 0) red4[wid] = part;
    __syncthreads();                                   // B1: v + partials
    double sigma = red4[0]+red4[1]+red4[2]+red4[3];
    double alpha = v[k+1];
    double beta, tau, scale;
    if (sigma <= 1e-280){ tau = 0.0; beta = alpha; scale = 0.0; }
    else {
      beta = -copysign(sqrt(alpha*alpha + sigma), alpha);
      tau = (beta - alpha)/beta;
      scale = 1.0/(alpha - beta);
    }
    if (tid == 0){ dd[k] = A[(size_t)k*NN + k]; ee[k] = beta; tau_s[k] = tau; }
    if (tau != 0.0){
      // store scaled Householder vector in A column (for back-transform);
      // LDS v stays UNSCALED — scale folded into the algebra below.
      for (int i = k+2+tid; i < NN; i += 256) A[(size_t)i*NN + k] = v[i]*scale;
      // p_i = tau * (A[i][k+1] + scale * sum_{j>=k+2} A[i][j] * v[j])
      for (int i = k+1+wid; i < NN; i += 4){
        const double* Ai = A + (size_t)i*NN;
        double s = 0.0;
        for (int j = k+2+lane; j < NN; j += 64) s += Ai[j]*v[j];
        s = waveSumD(s);
        if (lane == 0) p[i] = tau*(Ai[k+1] + scale*s);
      }
      __syncthreads();                                 // B2: p complete
      // vtp = u.p ;  u[k+1]=1, u[i]=v[i]*scale (i>=k+2)
      double pp = 0.0;
      for (int i = k+2+tid; i < NN; i += 256) pp += v[i]*scale*p[i];
      pp = waveSumD(pp);
      if (lane == 0) red4[wid] = pp;
      __syncthreads();                                 // B3
      double vtp = red4[0]+red4[1]+red4[2]+red4[3] + p[k+1];
      double Kc = 0.5*tau*vtp;
      // w = p - Kc*u  (store into p)
      if (tid == 0) p[k+1] -= Kc;
      for (int i = k+2+tid; i < NN; i += 256) p[i] -= Kc*v[i]*scale;
      __syncthreads();                                 // B4: w complete
      // A -= u w^T + w u^T  (trailing block)
      for (int i = k+1+wid; i < NN; i += 4){
        double ui = (i == k+1) ? 1.0 : v[i]*scale;
        double wi = p[i];
        double* Ai = A + (size_t)i*NN;
        for (int j = k+1+lane; j < NN; j += 64){
          double uj = (j == k+1) ? 1.0 : v[j]*scale;
          Ai[j] -= ui*p[j] + wi*uj;
        }
      }
      __syncthreads();                                 // B5: A ready for next k
    } else {
      __syncthreads();                                 // keep barrier count uniform
    }
  }
  if (tid == 0){
    dd[NN-2] = A[(size_t)(NN-2)*NN + NN-2];
    ee[NN-2] = A[(size_t)(NN-1)*NN + NN-2];
    dd[NN-1] = A[(size_t)(NN-1)*NN + NN-1];
  }
  __syncthreads();

  // ---- bisection (wave 0) + serial LU/inverse-iteration (lane 0) ----
  if (wid == 0){
    double mn = 1e300, mx = -1e300;
    for (int i = lane; i < NN; i += 64){
      double r = (i > 0 ? fabs(ee[i-1]) : 0.0) + (i < NN-1 ? fabs(ee[i]) : 0.0);
      mn = fmin(mn, dd[i]-r); mx = fmax(mx, dd[i]+r);
    }
#pragma unroll
    for (int o = 32; o > 0; o >>= 1){
      mn = fmin(mn, __shfl_down(mn, o));
      mx = fmax(mx, __shfl_down(mx, o));
    }
    mn = __shfl(mn, 0); mx = __shfl(mx, 0);
    double lo = mn - 1e-8 - 1e-9*fabs(mn);
    double hi = mx + 1e-8 + 1e-9*fabs(mx);
    for (int it = 0; it < 10; ++it){
      double lam = lo + (hi-lo)*((double)(lane+1)/65.0);
      int cnt = 0;
      double q = dd[0] - lam;
      if (q < 0.0) cnt++;
      for (int i2 = 1; i2 < NN; ++i2){
        double den = q;
        if (fabs(den) < 1e-280) den = (den < 0.0) ? -1e-280 : 1e-280;
        q = dd[i2] - lam - ee[i2-1]*ee[i2-1]/den;
        if (q < 0.0) cnt++;
      }
      unsigned long long bal = __ballot(cnt >= 2);
      if (bal == 0ull){
        lo = lo + (hi-lo)*(64.0/65.0);
      } else {
        int j0 = __ffsll(bal) - 1;
        double nl = lo + (hi-lo)*((double)j0/65.0);
        double nh = lo + (hi-lo)*((double)(j0+1)/65.0);
        lo = nl; hi = nh;
      }
    }
    double lam1 = 0.5*(lo+hi);

    if (lane == 0){
      for (int i = 0; i < NN; ++i) lu_d[i] = dd[i] - lam1;
      for (int i = 0; i < NN-1; ++i){ lu_dl[i] = ee[i]; lu_du[i] = ee[i]; }
      for (int i = 0; i < NN-2; ++i) lu_du2[i] = 0.0;
      for (int i = 0; i < NN-1; ++i){
        if (fabs(lu_d[i]) >= fabs(lu_dl[i])){
          double di = lu_d[i];
          if (fabs(di) < 1e-30){ di = (di < 0.0) ? -1e-30 : 1e-30; lu_d[i] = di; }
          double fact = lu_dl[i]/di;
          lu_dl[i] = fact;
          lu_d[i+1] -= fact*lu_du[i];
          lu_piv[i] = 0;
        } else {
          double fact = lu_d[i]/lu_dl[i];
          lu_d[i] = lu_dl[i];
          double tmp = lu_d[i+1];
          lu_d[i+1] = lu_du[i] - fact*tmp;
          if (i < NN-2){ lu_du2[i] = lu_du[i+1]; lu_du[i+1] = -fact*lu_du[i+1]; }
          lu_du[i] = tmp;
          lu_dl[i] = fact;
          lu_piv[i] = 1;
        }
      }
      if (fabs(lu_d[NN-1]) < 1e-30)
        lu_d[NN-1] = (lu_d[NN-1] < 0.0) ? -1e-30 : 1e-30;
      for (int i = 0; i < NN; ++i) yv[i] = 1.0 + 0.001*(double)((i*37)%29);
      for (int round = 0; round < 2; ++round){
        for (int i = 0; i < NN-1; ++i){
          if (lu_piv[i] == 0){
            yv[i+1] -= lu_dl[i]*yv[i];
          } else {
            double t = yv[i]; yv[i] = yv[i+1]; yv[i+1] = t - lu_dl[i]*yv[i];
          }
        }
        double mx1 = 0.0;
        for (int i = 0; i < NN; ++i) mx1 = fmax(mx1, fabs(yv[i]));
        double inv1 = (mx1 > 0.0 && isfinite(mx1)) ? 1.0/mx1 : 1.0;
        for (int i = 0; i < NN; ++i) yv[i] *= inv1;
        yv[NN-1] = yv[NN-1]/lu_d[NN-1];
        yv[NN-2] = (yv[NN-2] - lu_du[NN-2]*yv[NN-1])/lu_d[NN-2];
        for (int i = NN-3; i >= 0; --i)
          yv[i] = (yv[i] - lu_du[i]*yv[i+1] - lu_du2[i]*yv[i+2])/lu_d[i];
        double mxv = 0.0;
        for (int i = 0; i < NN; ++i) mxv = fmax(mxv, fabs(yv[i]));
        double inv = (mxv > 0.0 && isfinite(mxv)) ? 1.0/mxv : 1.0;
        for (int i = 0; i < NN; ++i){
          double val = yv[i]*inv;
          if (!isfinite(val)) val = 0.0;
          yv[i] = val;
        }
      }
    }
  }
  __syncthreads();                                     // yv ready for all waves

  // ---- back-transform: y <- H_0 ... H_{n-3} y ----
  for (int k = NN-3; k >= 0; --k){
    double tau = tau_s[k];
    if (tau != 0.0){
      double part = 0.0;
      for (int i = k+1+tid; i < NN; i += 256){
        double vi = (i == k+1) ? 1.0 : A[(size_t)i*NN + k];
        part += vi*yv[i];
      }
      part = waveSumD(part);
      if (lane == 0) red4[wid] = part;
      __syncthreads();
      double s = tau*(red4[0]+red4[1]+red4[2]+red4[3]);
      for (int i = k+1+tid; i < NN; i += 256){
        double vi = (i == k+1) ? 1.0 : A[(size_t)i*NN + k];
        yv[i] -= s*vi;
      }
    }
    __syncthreads();
  }

  // ---- Gram-Schmidt against v0 = sqrt(d) + normalize ----
  {
    double pd = 0.0, pn2 = 0.0;
    for (int i = tid; i < NN; i += 256){
      double sd = sqrt(darr[g*NN + i]);
      pd += sd*yv[i];
      pn2 += darr[g*NN + i];
    }
    pd = waveSumD(pd); pn2 = waveSumD(pn2);
    __shared__ double redB[4], redC[4];
    if (lane == 0){ redB[wid] = pd; redC[wid] = pn2; }
    __syncthreads();
    double dot = redB[0]+redB[1]+redB[2]+redB[3];
    double n2  = redC[0]+redC[1]+redC[2]+redC[3];
    double coef = dot/fmax(n2, 1e-300);
    for (int i = tid; i < NN; i += 256) yv[i] -= coef*sqrt(darr[g*NN + i]);
    __syncthreads();
    double pn = 0.0;
    for (int i = tid; i < NN; i += 256) pn += yv[i]*yv[i];
    pn = waveSumD(pn);
    if (lane == 0) redB[wid] = pn;
    __syncthreads();
    double nrm = sqrt(redB[0]+redB[1]+redB[2]+redB[3]);
    double inv = (nrm > 0.0 && isfinite(nrm)) ? 1.0/nrm : 0.0;
    for (int i = tid; i < NN; i += 256){
      double val = yv[i]*inv;
      if (!isfinite(val)) val = 0.0;
      v1out[g*NN + i] = val;
    }
  }
}

// kmeans on row-normalized [sqrt(d)/||.||, v1]  (fp64)
__global__ __launch_bounds__(256) void k_sg_kmeans(const double* __restrict__ darr,
                                                   const double* __restrict__ v1,
                                                   int* __restrict__ labels){
  __shared__ double px[NN], py[NN], cx[96], cy[96];
  __shared__ int lab[NN];
  __shared__ double red[16];
  int g = blockIdx.x, tid = threadIdx.x;
  double part = 0.0;
  for (int i = tid; i < NN; i += 256) part += darr[g*NN + i];
  double sumd = blockSumD(part, red);
  double invn = 1.0/sqrt(fmax(sumd, 1e-300));
  for (int i = tid; i < NN; i += 256){
    double h0 = sqrt(darr[g*NN + i])*invn;
    double h1 = v1[g*NN + i];
    double rn = sqrt(h0*h0 + h1*h1);
    double ax = h0/rn, ay = h1/rn;
    if (!isfinite(ax)) ax = 0.0;
    if (!isfinite(ay)) ay = 0.0;
    px[i] = ax; py[i] = ay;
  }
  __syncthreads();
  if (tid < 96){ cx[tid] = px[tid]; cy[tid] = py[tid]; }
  __syncthreads();
  for (int it = 0; it <= 10; ++it){
    if (tid < NN){
      double bx = px[tid], by = py[tid];
      double best = 1e300; int bi = 0;
      for (int a = 0; a < 96; ++a){
        double dx = bx - cx[a], dy = by - cy[a];
        double d2 = dx*dx + dy*dy;
        if (d2 < best){ best = d2; bi = a; }
      }
      lab[tid] = bi;
    }
    __syncthreads();
    if (it == 10) break;
    if (tid < 96){
      int c = 0; double sx = 0.0, sy = 0.0;
      for (int i = 0; i < NN; ++i){
        if (lab[i] == tid){ c++; sx += px[i]; sy += py[i]; }
      }
      if (c > 0){ cx[tid] = sx/(double)c; cy[tid] = sy/(double)c; }
      else      { cx[tid] = px[tid];      cy[tid] = py[tid]; }
    }
    __syncthreads();
  }
  if (tid < NN) labels[g*NN + tid] = lab[tid];
}

// S = pos_alpha + neg_alpha (fp64 in, fp32 out)
__global__ void k_sg_alpha(const double* __restrict__ esym, const int* __restrict__ labels,
                           float* __restrict__ S){
  __shared__ int lbs[NN];
  int g = blockIdx.x, j = threadIdx.x;
  if (j < NN) lbs[j] = labels[g*NN + j];
  __syncthreads();
  const double* E = esym + (size_t)g*NN*NN;
  const double NEG = -100000000.0;
  int lj = lbs[j];
  double mp = -1e300, mn = -1e300;
  for (int i = 0; i < NN; ++i){
    double w = E[i*NN + j];
    bool sm = (lbs[i] == lj);
    double vp = sm ? w : w*NEG; vp = vp > 0.0 ? vp : 0.2*vp;
    double vn = sm ? w*NEG : w; vn = vn > 0.0 ? vn : 0.2*vn;
    mp = fmax(mp, vp); mn = fmax(mn, vn);
  }
  double sp = 0.0, sn = 0.0;
  for (int i = 0; i < NN; ++i){
    double w = E[i*NN + j];
    bool sm = (lbs[i] == lj);
    double vp = sm ? w : w*NEG; vp = vp > 0.0 ? vp : 0.2*vp;
    double vn = sm ? w*NEG : w; vn = vn > 0.0 ? vn : 0.2*vn;
    sp += exp(vp - mp); sn += exp(vn - mn);
  }
  float* So = S + (size_t)g*NN*NN;
  for (int i = 0; i < NN; ++i){
    double w = E[i*NN + j];
    bool sm = (lbs[i] == lj);
    double vp = sm ? w : w*NEG; vp = vp > 0.0 ? vp : 0.2*vp;
    double vn = sm ? w*NEG : w; vn = vn > 0.0 ? vn : 0.2*vn;
    So[i*NN + j] = (float)(exp(vp - mp)/sp + exp(vn - mn)/sn);
  }
}

// h_out[i,:] = sum_j S[i,j] * relu(h_in[j,:]) per group
__global__ __launch_bounds__(320) void k_sg_feat(const float* __restrict__ S,
                                                 const float* __restrict__ hin,
                                                 float* __restrict__ hout){
  int r = blockIdx.x;
  int g = r / NN, li = r - g*NN;
  int dh = threadIdx.x;
  const float* Srow = S + (size_t)g*NN*NN + (size_t)li*NN;
  const float* hb = hin + (size_t)g*NN*DH;
  float acc = 0.f;
  for (int j = 0; j < NN; ++j){
    float w = Srow[j];
    float x = hb[(size_t)j*DH + dh];
    acc += w*(x > 0.f ? x : 0.f);
  }
  hout[(size_t)r*DH + dh] = acc;
}

// ---------------- host ----------------

extern "C" void kernel_launch(void* const* d_in, const int* in_sizes, int n_in,
                              void* d_out, int out_size, void* d_ws, size_t ws_size,
                              hipStream_t stream){
  (void)n_in; (void)out_size; (void)ws_size;

  // ---- workspace layout (float offsets) ----
  float* ws = (float*)d_ws;
  float* inp   = ws;                       // 98304
  float* gates = ws + 98304;               // 1966080
  float* hA    = ws + 2064384;             // 491520
  float* hB    = ws + 2555904;             // 491520
  float* cD    = ws + 3047424;             // 491520
  float* traj  = ws + 3538944;             // 3072
  double* sself_d  = (double*)(ws + 3542016);  // 3072 f
  double* sother_d = (double*)(ws + 3545088);  // 3072 f
  double* darr_d   = (double*)(ws + 3548160);  // 3072 f
  double* v1_d     = (double*)(ws + 3551232);  // 3072 f
  int*    labels   = (int*)(ws + 3554304);     // 1536
  // fp64 graph matrices overlay the (dead) gates buffer:
  double* edge_d = (double*)gates;             // 589824 f
  double* esym_d = (double*)(gates + 589824);  // 589824 f
  double* A_d    = (double*)(gates + 1179648); // 589824 f
  float*  Smat   = gates;                      // fp32 S reuses edge_d space (dead by then)
  // fp32 parameter arena:
  float* a_traj = ws + 3555840;            // 61440
  float* a_z    = ws + 3617280;            // 512
  float* a_Wemb = ws + 3617792;            // 128
  float* a_bemb = ws + 3617920;            // 64
  float* a_Wihe = ws + 3617984;            // 65536
  float* a_Whhe = ws + 3683520;            // 262144
  float* a_bihe = ws + 3945664;            // 1024
  float* a_bhhe = ws + 3946688;            // 1024
  float* a_Wihd = ws + 3947712;            // 81920
  float* a_Whhd = ws + 4029632;            // 409600
  float* a_bihd = ws + 4439232;            // 1280
  float* a_bhhd = ws + 4440512;            // 1280
  float* a_Wout = ws + 4441792;            // 640
  float* a_bout = ws + 4442432;            // 64
  float* a_Wne  = ws + 4442496;            // 20480
  float* a_bne  = ws + 4462976;            // 64
  float* a_Watt = ws + 4463040;            // 128
  float* a_batt = ws + 4463168;            // 64
  int* cnt  = (int*)(ws + 4463232);
  int* flag = (int*)(ws + 4463233);        // ~17.0 MiB total

  // ---- dtype probe ----
  k_zero_int<<<1, 64, 0, stream>>>(cnt, 2);
  k_probe<<<256, 256, 0, stream>>>((const unsigned short*)d_in[1], in_sizes[1], cnt);
  k_flag<<<1, 1, 0, stream>>>(cnt, flag);

  // ---- convert all float inputs to fp32 (enc h/c straight into hB/cD) ----
  CvtArgs ca;
  float* dsts[20] = { a_traj, hB, cD, a_z, a_Wemb, a_bemb, a_Wihe, a_Whhe, a_bihe,
                      a_bhhe, a_Wihd, a_Whhd, a_bihd, a_bhhd, a_Wout, a_bout,
                      a_Wne, a_bne, a_Watt, a_batt };
  for (int i = 0; i < 20; ++i){
    ca.src[i] = d_in[i];
    ca.dst[i] = dsts[i];
    ca.n[i]   = in_sizes[i];
  }
  k_convert<<<dim3(512, 20), 256, 0, stream>>>(ca, flag);

  // ---- encoder LSTM, 8 steps ----
  for (int t = 0; t < 8; ++t){
    k_embed<<<BB, 64, 0, stream>>>(a_traj + (size_t)t*BB*2, a_Wemb, a_bemb, inp);
    k_gates<<<dim3(1024/64, BB/64), 256, 0, stream>>>(inp, a_Wihe, 64, hB, a_Whhe, EHID,
                                                      a_bihe, a_bhhe, gates, 1024);
    k_lstm<<<(BB*EHID+255)/256, 256, 0, stream>>>(gates, cD, hB, EHID);
  }

  // ---- decoder init ----
  k_concat<<<(BB*DH+255)/256, 256, 0, stream>>>(hB, a_z, hA);
  k_zero_f<<<(BB*DH+255)/256, 256, 0, stream>>>(cD, BB*DH);
  k_copy_f<<<(BB*2+255)/256, 256, 0, stream>>>(a_traj + (size_t)7*BB*2, traj, BB*2);

  float* hcur = hA;
  float* hoth = hB;
  for (int i = 0; i < PRED; ++i){
    k_embed<<<BB, 64, 0, stream>>>(traj, a_Wemb, a_bemb, inp);
    if (i == 4){
      k_sg_emb<<<BB, 64, 0, stream>>>(hcur, a_Wne, a_bne, a_Watt, sself_d, sother_d);
      k_sg_edgecol<<<NG, NN, 0, stream>>>(sself_d, sother_d, a_batt, edge_d);
      k_sg_sym<<<(NG*NN*NN+255)/256, 256, 0, stream>>>(edge_d, esym_d);
      k_sg_dsum<<<(NG*NN+255)/256, 256, 0, stream>>>(esym_d, darr_d);
      k_sg_lsym<<<(NG*NN*NN+255)/256, 256, 0, stream>>>(esym_d, darr_d, A_d);
      k_sg_eigen<<<NG, 256, 0, stream>>>(A_d, darr_d, v1_d);
      k_sg_kmeans<<<NG, 256, 0, stream>>>(darr_d, v1_d, labels);
      k_sg_alpha<<<NG, NN, 0, stream>>>(esym_d, labels, Smat);
      k_sg_feat<<<BB, DH, 0, stream>>>(Smat, hcur, hoth);
      float* tmp = hcur; hcur = hoth; hoth = tmp;
    }
    k_gates<<<dim3((4*DH)/64, BB/64), 256, 0, stream>>>(inp, a_Wihd, 64, hcur, a_Whhd, DH,
                                                        a_bihd, a_bhhd, gates, 4*DH);
    k_lstm<<<(BB*DH+255)/256, 256, 0, stream>>>(gates, cD, hcur, DH);
    k_outproj<<<BB, 64, 0, stream>>>(hcur, a_Wout, a_bout, traj, d_out, i, flag);
  }
}

// Round 8
// 5434.011 us; speedup vs baseline: 2.6161x; 1.2576x over previous
//
#include <hip/hip_runtime.h>
#include <hip/hip_bf16.h>

typedef __hip_bfloat16 bf16;

#define NN 192      // nodes per group
#define NG 8        // groups
#define BB 1536     // batch
#define EHID 256
#define DH 320      // decoder hidden
#define PRED 12
#define TRI ((NN*(NN+1))/2)   // 18528 packed lower-triangle elements

__device__ __forceinline__ float waveSum(float v){
#pragma unroll
  for (int o = 32; o > 0; o >>= 1) v += __shfl_down(v, o);
  return v;
}
__device__ __forceinline__ double waveSumD(double v){
#pragma unroll
  for (int o = 32; o > 0; o >>= 1) v += __shfl_down(v, o);
  return v;
}

__device__ __forceinline__ double blockSumD(double v, double* red){
  int lane = threadIdx.x & 63, wid = threadIdx.x >> 6, nw = (int)blockDim.x >> 6;
  double s = waveSumD(v);
  __syncthreads();
  if (lane == 0) red[wid] = s;
  __syncthreads();
  if (wid == 0){
    double t = (lane < nw) ? red[lane] : 0.0;
    t = waveSumD(t);
    if (lane == 0) red[0] = t;
  }
  __syncthreads();
  return red[0];
}

// ---------------- dtype probe + conversion ----------------

__global__ void k_zero_int(int* __restrict__ p, int n){
  int i = blockIdx.x*blockDim.x + threadIdx.x;
  if (i < n) p[i] = 0;
}
__global__ void k_zero_f(float* __restrict__ p, int n){
  int i = blockIdx.x*blockDim.x + threadIdx.x;
  if (i < n) p[i] = 0.f;
}

__global__ void k_probe(const unsigned short* __restrict__ src, int n, int* __restrict__ cnt){
  int tid = blockIdx.x*blockDim.x + threadIdx.x;
  int stride = gridDim.x*blockDim.x;
  int bad = 0;
  for (int j = tid; j < n; j += stride){
    float v = __uint_as_float(((unsigned int)src[j]) << 16);
    if (!(fabsf(v) < 100.f)) bad++;
  }
#pragma unroll
  for (int o = 32; o > 0; o >>= 1) bad += __shfl_down(bad, o);
  if ((threadIdx.x & 63) == 0 && bad > 0) atomicAdd(cnt, bad);
}
__global__ void k_flag(const int* __restrict__ cnt, int* __restrict__ flag){
  *flag = (*cnt > 4096) ? 1 : 0;        // 1 = inputs are fp32, 0 = bf16
}

struct CvtArgs {
  const void* src[20];
  float*      dst[20];
  int         n[20];
};

__global__ void k_convert(CvtArgs a, const int* __restrict__ flag){
  int id = blockIdx.y;
  int n = a.n[id];
  float* d = a.dst[id];
  int t = blockIdx.x*blockDim.x + threadIdx.x;
  int stride = gridDim.x*blockDim.x;
  if (*flag == 0){
    const bf16* s = (const bf16*)a.src[id];
    for (int j = t; j < n; j += stride) d[j] = __bfloat162float(s[j]);
  } else {
    const float* s = (const float*)a.src[id];
    for (int j = t; j < n; j += stride) d[j] = s[j];
  }
}

// ---------------- elementwise / small kernels ----------------

__global__ void k_embed(const float* __restrict__ in, const float* __restrict__ W,
                        const float* __restrict__ b, float* __restrict__ out){
  int r = blockIdx.x, e = threadIdx.x;
  float x = in[r*2], y = in[r*2+1];
  float v = W[e*2]*x + W[e*2+1]*y + b[e];
  out[r*64+e] = v > 0.f ? v : 0.f;
}

__global__ void k_concat(const float* __restrict__ henc, const float* __restrict__ z,
                         float* __restrict__ h){
  int idx = blockIdx.x*blockDim.x + threadIdx.x;
  if (idx >= BB*DH) return;
  int b = idx / DH, j = idx - b*DH;
  h[idx] = (j < EHID) ? henc[b*EHID + j] : z[(b/NN)*64 + (j - EHID)];
}

__global__ void k_copy_f(const float* __restrict__ in, float* __restrict__ dst, int n){
  int i = blockIdx.x*blockDim.x + threadIdx.x;
  if (i < n) dst[i] = in[i];
}

// gates = A1@W1^T + A2@W2^T + b1 + b2 ; M=1536, N,K multiples of 32/64
__global__ __launch_bounds__(256) void k_gates(
    const float* __restrict__ A1, const float* __restrict__ W1, int K1,
    const float* __restrict__ A2, const float* __restrict__ W2, int K2,
    const float* __restrict__ b1, const float* __restrict__ b2,
    float* __restrict__ C, int N){
  __shared__ __align__(16) float As[32][68];
  __shared__ __align__(16) float Ws[32][68];
  int tid = threadIdx.x;
  int tx = tid & 15, ty = tid >> 4;
  int n0 = blockIdx.x * 64, m0 = blockIdx.y * 64;
  float acc[4][4] = {};
  for (int ph = 0; ph < 2; ++ph){
    const float* A = ph ? A2 : A1;
    const float* W = ph ? W2 : W1;
    int K = ph ? K2 : K1;
    for (int k0 = 0; k0 < K; k0 += 32){
      {
        int am = tid >> 2, ak = (tid & 3) * 8;
        const float* srcA = A + (size_t)(m0+am)*K + k0 + ak;
        float4 f0 = *(const float4*)(srcA);
        float4 f1 = *(const float4*)(srcA+4);
        As[ak+0][am]=f0.x; As[ak+1][am]=f0.y; As[ak+2][am]=f0.z; As[ak+3][am]=f0.w;
        As[ak+4][am]=f1.x; As[ak+5][am]=f1.y; As[ak+6][am]=f1.z; As[ak+7][am]=f1.w;
        const float* srcW = W + (size_t)(n0+am)*K + k0 + ak;
        float4 w0 = *(const float4*)(srcW);
        float4 w1 = *(const float4*)(srcW+4);
        Ws[ak+0][am]=w0.x; Ws[ak+1][am]=w0.y; Ws[ak+2][am]=w0.z; Ws[ak+3][am]=w0.w;
        Ws[ak+4][am]=w1.x; Ws[ak+5][am]=w1.y; Ws[ak+6][am]=w1.z; Ws[ak+7][am]=w1.w;
      }
      __syncthreads();
#pragma unroll
      for (int k = 0; k < 32; ++k){
        float4 a0 = *(const float4*)&As[k][ty*4];
        float4 b0 = *(const float4*)&Ws[k][tx*4];
        float av[4] = {a0.x, a0.y, a0.z, a0.w};
        float bv[4] = {b0.x, b0.y, b0.z, b0.w};
#pragma unroll
        for (int i = 0; i < 4; ++i)
#pragma unroll
          for (int j = 0; j < 4; ++j)
            acc[i][j] += av[i]*bv[j];
      }
      __syncthreads();
    }
  }
  float bs[4];
#pragma unroll
  for (int j = 0; j < 4; ++j){
    int col = n0 + tx*4 + j;
    bs[j] = b1[col] + b2[col];
  }
#pragma unroll
  for (int i = 0; i < 4; ++i){
    int row = m0 + ty*4 + i;
    float4 v;
    v.x = acc[i][0] + bs[0]; v.y = acc[i][1] + bs[1];
    v.z = acc[i][2] + bs[2]; v.w = acc[i][3] + bs[3];
    *(float4*)&C[(size_t)row*N + n0 + tx*4] = v;
  }
}

__global__ void k_lstm(const float* __restrict__ gates, float* __restrict__ c,
                       float* __restrict__ h, int H){
  int idx = blockIdx.x*blockDim.x + threadIdx.x;
  if (idx >= BB*H) return;
  int b = idx / H, j = idx - b*H;
  const float* g = gates + (size_t)b*4*H;
  float gi = g[j], gf = g[H+j], gg = g[2*H+j], go = g[3*H+j];
  float si = 1.f/(1.f+expf(-gi));
  float sf = 1.f/(1.f+expf(-gf));
  float so = 1.f/(1.f+expf(-go));
  float cc = sf*c[idx] + si*tanhf(gg);
  c[idx] = cc;
  h[idx] = so*tanhf(cc);
}

// h(1536x320) -> traj(1536x2) fp32 + output slice `step` (fp32 or bf16 per flag)
__global__ void k_outproj(const float* __restrict__ h, const float* __restrict__ W,
                          const float* __restrict__ bo, float* __restrict__ traj,
                          void* __restrict__ outbase, int step, const int* __restrict__ flag){
  int b = blockIdx.x, lane = threadIdx.x;
  const float* hb = h + (size_t)b*DH;
  float a0 = 0.f, a1 = 0.f;
  for (int k = lane; k < DH; k += 64){
    float hv = hb[k];
    a0 += hv*W[k];
    a1 += hv*W[DH+k];
  }
  a0 = waveSum(a0); a1 = waveSum(a1);
  if (lane == 0){
    a0 += bo[0]; a1 += bo[1];
    traj[b*2] = a0; traj[b*2+1] = a1;
    size_t idx = (size_t)step*BB*2 + (size_t)b*2;
    if (*flag == 0){
      bf16* o = (bf16*)outbase;
      o[idx] = __float2bfloat16(a0); o[idx+1] = __float2bfloat16(a1);
    } else {
      float* o = (float*)outbase;
      o[idx] = a0; o[idx+1] = a1;
    }
  }
}

// ---------------- signed-graph kernels (fp64 numeric path) ----------------

__global__ void k_sg_emb(const float* __restrict__ h, const float* __restrict__ Wne,
                         const float* __restrict__ bne, const float* __restrict__ Watt,
                         double* __restrict__ sself, double* __restrict__ sother){
  int node = blockIdx.x, e = threadIdx.x;
  const float* hb = h + (size_t)node*DH;
  double acc = (double)bne[e];
  for (int k = 0; k < DH; ++k) acc += (double)hb[k]*(double)Wne[e*DH+k];
  double po = acc * (double)Watt[e];       // a_other = W_att[0, :64]
  double ps = acc * (double)Watt[64+e];    // a_self  = W_att[0, 64:]
  po = waveSumD(po); ps = waveSumD(ps);
  if (e == 0){ sother[node] = po; sself[node] = ps; }
}

__global__ void k_sg_edgecol(const double* __restrict__ sself, const double* __restrict__ sother,
                             const float* __restrict__ batt, double* __restrict__ edge){
  int g = blockIdx.x, j = threadIdx.x;
  const double* ss = sself + g*NN;
  double bb = (double)batt[0];
  double sj = sother[g*NN + j];
  double m = -1e300;
  for (int i = 0; i < NN; ++i){
    double e = ss[i] + sj + bb; e = e > 0.0 ? e : 0.2*e;
    m = fmax(m, e);
  }
  double sum = 0.0;
  for (int i = 0; i < NN; ++i){
    double e = ss[i] + sj + bb; e = e > 0.0 ? e : 0.2*e;
    sum += exp(e - m);
  }
  double* E = edge + (size_t)g*NN*NN;
  for (int i = 0; i < NN; ++i){
    double e = ss[i] + sj + bb; e = e > 0.0 ? e : 0.2*e;
    E[i*NN + j] = exp(e - m)/sum;
  }
}

__global__ void k_sg_sym(const double* __restrict__ edge, double* __restrict__ esym){
  int idx = blockIdx.x*blockDim.x + threadIdx.x;
  if (idx >= NG*NN*NN) return;
  int g = idx / (NN*NN), r = idx - g*NN*NN;
  int i = r / NN, j = r - i*NN;
  const double* E = edge + (size_t)g*NN*NN;
  esym[idx] = (i <= j) ? E[i*NN + j] : E[j*NN + i];
}

__global__ void k_sg_dsum(const double* __restrict__ esym, double* __restrict__ darr){
  int i = blockIdx.x*blockDim.x + threadIdx.x;
  if (i >= NG*NN) return;
  int g = i / NN, li = i - g*NN;
  const double* E = esym + (size_t)g*NN*NN + (size_t)li*NN;
  double s = 0.0;
  for (int j = 0; j < NN; ++j) s += E[j];
  darr[i] = fmax(s, 1e-300);
}

// packed lower-triangle L_sym
__global__ void k_sg_lsym(const double* __restrict__ esym, const double* __restrict__ darr,
                          double* __restrict__ Lpack){
  int idx = blockIdx.x*blockDim.x + threadIdx.x;
  if (idx >= NG*NN*NN) return;
  int g = idx / (NN*NN), r = idx - g*NN*NN;
  int i = r / NN, j = r - i*NN;
  if (j > i) return;
  double w = esym[idx];
  double lij = (i == j) ? (darr[g*NN+i] - w) : (-w);
  Lpack[(size_t)g*TRI + i*(i+1)/2 + j] = lij / (sqrt(darr[g*NN+i])*sqrt(darr[g*NN+j]));
}

// LDS-RESIDENT packed-symmetric Householder tridiag + Sturm bisection +
// inverse iteration + back-transform + Gram-Schmidt vs v0=sqrt(d).
// 256 threads/group, dynamic LDS = (TRI + 8*NN + 8)*8 = 160576 B.
// Householder vectors stored in dead sub-column-k slots; tau on dead diagonal.
__global__ __launch_bounds__(256) void k_sg_eigen(const double* __restrict__ Lpack,
                                                  const double* __restrict__ darr,
                                                  double* __restrict__ v1out){
  extern __shared__ double lds[];
  double* tri   = lds;                 // TRI
  double* v     = lds + TRI;           // NN
  double* p     = v + NN;              // NN
  double* dd    = p + NN;              // NN
  double* ee    = dd + NN;             // NN
  double* yv    = ee + NN;             // NN
  double* lu_d  = yv + NN;             // NN
  double* lu_du = lu_d + NN;           // NN
  double* lu_du2= lu_du + NN;          // NN
  double* redA  = lu_du2 + NN;         // 4
  double* redB  = redA + 4;            // 4
  double* lu_dl = v;                   // alias: v dead in LU phase
  int*    lu_piv= (int*)p;             // alias: p dead in LU phase

  int g = blockIdx.x, tid = threadIdx.x;
  int lane = tid & 63, wid = tid >> 6;  // 4 waves

  const double* src = Lpack + (size_t)g*TRI;
  for (int t = tid; t < TRI; t += 256) tri[t] = src[t];
  __syncthreads();

  // ---- tridiagonalization (all in LDS) ----
  for (int k = 0; k < NN-2; ++k){
    int m = NN-1-k;                      // trailing rows
    double part = 0.0;
    if (tid < m){
      int i = k+1+tid;
      double x = tri[i*(i+1)/2 + k];
      v[i] = x;
      if (i > k+1) part = x*x;
    }
    part = waveSumD(part);
    if (lane == 0) redA[wid] = part;
    __syncthreads();                                   // B1
    double sigma = redA[0]+redA[1]+redA[2]+redA[3];
    double alpha = v[k+1];
    double beta, tau, scale;
    if (sigma <= 1e-280){ tau = 0.0; beta = alpha; scale = 0.0; }
    else {
      beta = -copysign(sqrt(alpha*alpha + sigma), alpha);
      tau = (beta - alpha)/beta;
      scale = 1.0/(alpha - beta);
    }
    if (tid == 0){
      int dk = k*(k+1)/2 + k;
      dd[k] = tri[dk]; ee[k] = beta;
      tri[dk] = tau;                                   // stash tau (diag slot dead)
    }
    if (tau != 0.0){
      if (tid < m-1){                                  // store scaled u into col k
        int i = k+2+tid;
        tri[i*(i+1)/2 + k] = v[i]*scale;
      }
      // matvec: thread-per-row (uniform length n-1-k)
      if (tid < m){
        int i = k+1+tid;
        int bi = i*(i+1)/2;
        double s = 0.0;
        for (int j = k+2; j <= i; ++j) s += tri[bi + j]*v[j];
        for (int j = i+1; j < NN; ++j) s += tri[j*(j+1)/2 + i]*v[j];
        p[i] = tau*(tri[bi + k+1] + scale*s);
      }
      __syncthreads();                                 // B2: p complete
      double pk1 = p[k+1];                             // snapshot before B3 (race-free)
      double pp = 0.0;
      if (tid < m-1){ int i = k+2+tid; pp = v[i]*scale*p[i]; }
      pp = waveSumD(pp);
      if (lane == 0) redB[wid] = pp;
      __syncthreads();                                 // B3
      double vtp = redB[0]+redB[1]+redB[2]+redB[3] + pk1;
      double Kc = 0.5*tau*vtp;
      if (tid == 0) p[k+1] -= Kc;
      if (tid < m-1){ int i = k+2+tid; p[i] -= Kc*v[i]*scale; }
      __syncthreads();                                 // B4: w complete
      // rank-2: two balanced rows per thread (lengths r+1 and m-r sum to m+1)
      int half = (m+1) >> 1;
      if (tid < half){
        int r1 = tid, r2 = m-1-tid;
        {
          int i = k+1+r1, bi = i*(i+1)/2;
          double ui = (r1 == 0) ? 1.0 : v[i]*scale;
          double wi = p[i];
          for (int j = k+1; j <= i; ++j){
            double uj = (j == k+1) ? 1.0 : v[j]*scale;
            tri[bi+j] -= ui*p[j] + wi*uj;
          }
        }
        if (r2 != r1){
          int i = k+1+r2, bi = i*(i+1)/2;
          double ui = (r2 == 0) ? 1.0 : v[i]*scale;
          double wi = p[i];
          for (int j = k+1; j <= i; ++j){
            double uj = (j == k+1) ? 1.0 : v[j]*scale;
            tri[bi+j] -= ui*p[j] + wi*uj;
          }
        }
      }
      __syncthreads();                                 // B5
    } else {
      __syncthreads();
    }
  }
  if (tid == 0){
    dd[NN-2] = tri[(NN-2)*(NN-1)/2 + (NN-2)];
    ee[NN-2] = tri[(NN-1)*NN/2 + (NN-2)];
    dd[NN-1] = tri[(NN-1)*NN/2 + (NN-1)];
  }
  __syncthreads();

  // ---- bisection (wave 0) + serial LU/inverse-iteration (lane 0) ----
  if (wid == 0){
    double mn = 1e300, mx = -1e300;
    for (int i = lane; i < NN; i += 64){
      double r = (i > 0 ? fabs(ee[i-1]) : 0.0) + (i < NN-1 ? fabs(ee[i]) : 0.0);
      mn = fmin(mn, dd[i]-r); mx = fmax(mx, dd[i]+r);
    }
#pragma unroll
    for (int o = 32; o > 0; o >>= 1){
      mn = fmin(mn, __shfl_down(mn, o));
      mx = fmax(mx, __shfl_down(mx, o));
    }
    mn = __shfl(mn, 0); mx = __shfl(mx, 0);
    double lo = mn - 1e-8 - 1e-9*fabs(mn);
    double hi = mx + 1e-8 + 1e-9*fabs(mx);
    for (int it = 0; it < 10; ++it){
      double lam = lo + (hi-lo)*((double)(lane+1)/65.0);
      int cnt = 0;
      double q = dd[0] - lam;
      if (q < 0.0) cnt++;
      for (int i2 = 1; i2 < NN; ++i2){
        double den = q;
        if (fabs(den) < 1e-280) den = (den < 0.0) ? -1e-280 : 1e-280;
        q = dd[i2] - lam - ee[i2-1]*ee[i2-1]/den;
        if (q < 0.0) cnt++;
      }
      unsigned long long bal = __ballot(cnt >= 2);
      if (bal == 0ull){
        lo = lo + (hi-lo)*(64.0/65.0);
      } else {
        int j0 = __ffsll(bal) - 1;
        double nl = lo + (hi-lo)*((double)j0/65.0);
        double nh = lo + (hi-lo)*((double)(j0+1)/65.0);
        lo = nl; hi = nh;
      }
    }
    double lam1 = 0.5*(lo+hi);

    if (lane == 0){
      for (int i = 0; i < NN; ++i) lu_d[i] = dd[i] - lam1;
      for (int i = 0; i < NN-1; ++i){ lu_dl[i] = ee[i]; lu_du[i] = ee[i]; }
      for (int i = 0; i < NN-2; ++i) lu_du2[i] = 0.0;
      for (int i = 0; i < NN-1; ++i){
        if (fabs(lu_d[i]) >= fabs(lu_dl[i])){
          double di = lu_d[i];
          if (fabs(di) < 1e-30){ di = (di < 0.0) ? -1e-30 : 1e-30; lu_d[i] = di; }
          double fact = lu_dl[i]/di;
          lu_dl[i] = fact;
          lu_d[i+1] -= fact*lu_du[i];
          lu_piv[i] = 0;
        } else {
          double fact = lu_d[i]/lu_dl[i];
          lu_d[i] = lu_dl[i];
          double tmp = lu_d[i+1];
          lu_d[i+1] = lu_du[i] - fact*tmp;
          if (i < NN-2){ lu_du2[i] = lu_du[i+1]; lu_du[i+1] = -fact*lu_du[i+1]; }
          lu_du[i] = tmp;
          lu_dl[i] = fact;
          lu_piv[i] = 1;
        }
      }
      if (fabs(lu_d[NN-1]) < 1e-30)
        lu_d[NN-1] = (lu_d[NN-1] < 0.0) ? -1e-30 : 1e-30;
      for (int i = 0; i < NN; ++i) yv[i] = 1.0 + 0.001*(double)((i*37)%29);
      for (int round = 0; round < 2; ++round){
        for (int i = 0; i < NN-1; ++i){
          if (lu_piv[i] == 0){
            yv[i+1] -= lu_dl[i]*yv[i];
          } else {
            double t = yv[i]; yv[i] = yv[i+1]; yv[i+1] = t - lu_dl[i]*yv[i];
          }
        }
        double mx1 = 0.0;
        for (int i = 0; i < NN; ++i) mx1 = fmax(mx1, fabs(yv[i]));
        double inv1 = (mx1 > 0.0 && isfinite(mx1)) ? 1.0/mx1 : 1.0;
        for (int i = 0; i < NN; ++i) yv[i] *= inv1;
        yv[NN-1] = yv[NN-1]/lu_d[NN-1];
        yv[NN-2] = (yv[NN-2] - lu_du[NN-2]*yv[NN-1])/lu_d[NN-2];
        for (int i = NN-3; i >= 0; --i)
          yv[i] = (yv[i] - lu_du[i]*yv[i+1] - lu_du2[i]*yv[i+2])/lu_d[i];
        double mxv = 0.0;
        for (int i = 0; i < NN; ++i) mxv = fmax(mxv, fabs(yv[i]));
        double inv = (mxv > 0.0 && isfinite(mxv)) ? 1.0/mxv : 1.0;
        for (int i = 0; i < NN; ++i){
          double val = yv[i]*inv;
          if (!isfinite(val)) val = 0.0;
          yv[i] = val;
        }
      }
    }
  }
  __syncthreads();                                     // yv ready

  // ---- back-transform: y <- H_0 ... H_{n-3} y (vectors read from LDS tri) ----
  for (int k = NN-3; k >= 0; --k){
    double tau = tri[k*(k+1)/2 + k];
    if (tau != 0.0){
      int i = k+1+tid;
      double ui = 0.0, part = 0.0;
      if (tid < NN-1-k){
        ui = (tid == 0) ? 1.0 : tri[i*(i+1)/2 + k];
        part = ui*yv[i];
      }
      part = waveSumD(part);
      if (lane == 0) redA[wid] = part;
      __syncthreads();
      double s = tau*(redA[0]+redA[1]+redA[2]+redA[3]);
      if (tid < NN-1-k) yv[i] -= s*ui;
    }
    __syncthreads();
  }

  // ---- Gram-Schmidt against v0 = sqrt(d) + normalize ----
  {
    double pd = 0.0, pn2 = 0.0;
    for (int i = tid; i < NN; i += 256){
      double sd = sqrt(darr[g*NN + i]);
      pd += sd*yv[i];
      pn2 += darr[g*NN + i];
    }
    pd = waveSumD(pd); pn2 = waveSumD(pn2);
    if (lane == 0){ redA[wid] = pd; redB[wid] = pn2; }
    __syncthreads();
    double dot = redA[0]+redA[1]+redA[2]+redA[3];
    double n2  = redB[0]+redB[1]+redB[2]+redB[3];
    double coef = dot/fmax(n2, 1e-300);
    for (int i = tid; i < NN; i += 256) yv[i] -= coef*sqrt(darr[g*NN + i]);
    __syncthreads();
    double pn = 0.0;
    for (int i = tid; i < NN; i += 256) pn += yv[i]*yv[i];
    pn = waveSumD(pn);
    if (lane == 0) redA[wid] = pn;
    __syncthreads();
    double nrm = sqrt(redA[0]+redA[1]+redA[2]+redA[3]);
    double inv = (nrm > 0.0 && isfinite(nrm)) ? 1.0/nrm : 0.0;
    for (int i = tid; i < NN; i += 256){
      double val = yv[i]*inv;
      if (!isfinite(val)) val = 0.0;
      v1out[g*NN + i] = val;
    }
  }
}

// kmeans on row-normalized [sqrt(d)/||.||, v1]  (fp64)
__global__ __launch_bounds__(256) void k_sg_kmeans(const double* __restrict__ darr,
                                                   const double* __restrict__ v1,
                                                   int* __restrict__ labels){
  __shared__ double px[NN], py[NN], cx[96], cy[96];
  __shared__ int lab[NN];
  __shared__ double red[16];
  int g = blockIdx.x, tid = threadIdx.x;
  double part = 0.0;
  for (int i = tid; i < NN; i += 256) part += darr[g*NN + i];
  double sumd = blockSumD(part, red);
  double invn = 1.0/sqrt(fmax(sumd, 1e-300));
  for (int i = tid; i < NN; i += 256){
    double h0 = sqrt(darr[g*NN + i])*invn;
    double h1 = v1[g*NN + i];
    double rn = sqrt(h0*h0 + h1*h1);
    double ax = h0/rn, ay = h1/rn;
    if (!isfinite(ax)) ax = 0.0;
    if (!isfinite(ay)) ay = 0.0;
    px[i] = ax; py[i] = ay;
  }
  __syncthreads();
  if (tid < 96){ cx[tid] = px[tid]; cy[tid] = py[tid]; }
  __syncthreads();
  for (int it = 0; it <= 10; ++it){
    if (tid < NN){
      double bx = px[tid], by = py[tid];
      double best = 1e300; int bi = 0;
      for (int a = 0; a < 96; ++a){
        double dx = bx - cx[a], dy = by - cy[a];
        double d2 = dx*dx + dy*dy;
        if (d2 < best){ best = d2; bi = a; }
      }
      lab[tid] = bi;
    }
    __syncthreads();
    if (it == 10) break;
    if (tid < 96){
      int c = 0; double sx = 0.0, sy = 0.0;
      for (int i = 0; i < NN; ++i){
        if (lab[i] == tid){ c++; sx += px[i]; sy += py[i]; }
      }
      if (c > 0){ cx[tid] = sx/(double)c; cy[tid] = sy/(double)c; }
      else      { cx[tid] = px[tid];      cy[tid] = py[tid]; }
    }
    __syncthreads();
  }
  if (tid < NN) labels[g*NN + tid] = lab[tid];
}

// S = pos_alpha + neg_alpha (fp64 in, fp32 out)
__global__ void k_sg_alpha(const double* __restrict__ esym, const int* __restrict__ labels,
                           float* __restrict__ S){
  __shared__ int lbs[NN];
  int g = blockIdx.x, j = threadIdx.x;
  if (j < NN) lbs[j] = labels[g*NN + j];
  __syncthreads();
  const double* E = esym + (size_t)g*NN*NN;
  const double NEG = -100000000.0;
  int lj = lbs[j];
  double mp = -1e300, mn = -1e300;
  for (int i = 0; i < NN; ++i){
    double w = E[i*NN + j];
    bool sm = (lbs[i] == lj);
    double vp = sm ? w : w*NEG; vp = vp > 0.0 ? vp : 0.2*vp;
    double vn = sm ? w*NEG : w; vn = vn > 0.0 ? vn : 0.2*vn;
    mp = fmax(mp, vp); mn = fmax(mn, vn);
  }
  double sp = 0.0, sn = 0.0;
  for (int i = 0; i < NN; ++i){
    double w = E[i*NN + j];
    bool sm = (lbs[i] == lj);
    double vp = sm ? w : w*NEG; vp = vp > 0.0 ? vp : 0.2*vp;
    double vn = sm ? w*NEG : w; vn = vn > 0.0 ? vn : 0.2*vn;
    sp += exp(vp - mp); sn += exp(vn - mn);
  }
  float* So = S + (size_t)g*NN*NN;
  for (int i = 0; i < NN; ++i){
    double w = E[i*NN + j];
    bool sm = (lbs[i] == lj);
    double vp = sm ? w : w*NEG; vp = vp > 0.0 ? vp : 0.2*vp;
    double vn = sm ? w*NEG : w; vn = vn > 0.0 ? vn : 0.2*vn;
    So[i*NN + j] = (float)(exp(vp - mp)/sp + exp(vn - mn)/sn);
  }
}

// h_out[i,:] = sum_j S[i,j] * relu(h_in[j,:]) per group
__global__ __launch_bounds__(320) void k_sg_feat(const float* __restrict__ S,
                                                 const float* __restrict__ hin,
                                                 float* __restrict__ hout){
  int r = blockIdx.x;
  int g = r / NN, li = r - g*NN;
  int dh = threadIdx.x;
  const float* Srow = S + (size_t)g*NN*NN + (size_t)li*NN;
  const float* hb = hin + (size_t)g*NN*DH;
  float acc = 0.f;
  for (int j = 0; j < NN; ++j){
    float w = Srow[j];
    float x = hb[(size_t)j*DH + dh];
    acc += w*(x > 0.f ? x : 0.f);
  }
  hout[(size_t)r*DH + dh] = acc;
}

// ---------------- host ----------------

extern "C" void kernel_launch(void* const* d_in, const int* in_sizes, int n_in,
                              void* d_out, int out_size, void* d_ws, size_t ws_size,
                              hipStream_t stream){
  (void)n_in; (void)out_size; (void)ws_size;

  // ---- workspace layout (float offsets) ----
  float* ws = (float*)d_ws;
  float* inp   = ws;                       // 98304
  float* gates = ws + 98304;               // 1966080
  float* hA    = ws + 2064384;             // 491520
  float* hB    = ws + 2555904;             // 491520
  float* cD    = ws + 3047424;             // 491520
  float* traj  = ws + 3538944;             // 3072
  double* sself_d  = (double*)(ws + 3542016);  // 3072 f
  double* sother_d = (double*)(ws + 3545088);  // 3072 f
  double* darr_d   = (double*)(ws + 3548160);  // 3072 f
  double* v1_d     = (double*)(ws + 3551232);  // 3072 f
  int*    labels   = (int*)(ws + 3554304);     // 1536
  // fp64 graph matrices overlay the (dead) gates buffer:
  double* edge_d = (double*)gates;             // 589824 f
  double* esym_d = (double*)(gates + 589824);  // 589824 f
  double* Lpack  = (double*)(gates + 1179648); // packed: NG*TRI dbl = 296448 f
  float*  Smat   = gates;                      // fp32 S reuses edge_d space (dead by then)
  // fp32 parameter arena:
  float* a_traj = ws + 3555840;            // 61440
  float* a_z    = ws + 3617280;            // 512
  float* a_Wemb = ws + 3617792;            // 128
  float* a_bemb = ws + 3617920;            // 64
  float* a_Wihe = ws + 3617984;            // 65536
  float* a_Whhe = ws + 3683520;            // 262144
  float* a_bihe = ws + 3945664;            // 1024
  float* a_bhhe = ws + 3946688;            // 1024
  float* a_Wihd = ws + 3947712;            // 81920
  float* a_Whhd = ws + 4029632;            // 409600
  float* a_bihd = ws + 4439232;            // 1280
  float* a_bhhd = ws + 4440512;            // 1280
  float* a_Wout = ws + 4441792;            // 640
  float* a_bout = ws + 4442432;            // 64
  float* a_Wne  = ws + 4442496;            // 20480
  float* a_bne  = ws + 4462976;            // 64
  float* a_Watt = ws + 4463040;            // 128
  float* a_batt = ws + 4463168;            // 64
  int* cnt  = (int*)(ws + 4463232);
  int* flag = (int*)(ws + 4463233);        // ~17.0 MiB total

  // allow >64KB dynamic LDS for the eigen kernel (idempotent, host-side)
  const int EIG_LDS = (int)((TRI + 8*NN + 8) * sizeof(double));   // 160576
  hipFuncSetAttribute((const void*)k_sg_eigen,
                      hipFuncAttributeMaxDynamicSharedMemorySize, EIG_LDS);

  // ---- dtype probe ----
  k_zero_int<<<1, 64, 0, stream>>>(cnt, 2);
  k_probe<<<256, 256, 0, stream>>>((const unsigned short*)d_in[1], in_sizes[1], cnt);
  k_flag<<<1, 1, 0, stream>>>(cnt, flag);

  // ---- convert all float inputs to fp32 (enc h/c straight into hB/cD) ----
  CvtArgs ca;
  float* dsts[20] = { a_traj, hB, cD, a_z, a_Wemb, a_bemb, a_Wihe, a_Whhe, a_bihe,
                      a_bhhe, a_Wihd, a_Whhd, a_bihd, a_bhhd, a_Wout, a_bout,
                      a_Wne, a_bne, a_Watt, a_batt };
  for (int i = 0; i < 20; ++i){
    ca.src[i] = d_in[i];
    ca.dst[i] = dsts[i];
    ca.n[i]   = in_sizes[i];
  }
  k_convert<<<dim3(512, 20), 256, 0, stream>>>(ca, flag);

  // ---- encoder LSTM, 8 steps ----
  for (int t = 0; t < 8; ++t){
    k_embed<<<BB, 64, 0, stream>>>(a_traj + (size_t)t*BB*2, a_Wemb, a_bemb, inp);
    k_gates<<<dim3(1024/64, BB/64), 256, 0, stream>>>(inp, a_Wihe, 64, hB, a_Whhe, EHID,
                                                      a_bihe, a_bhhe, gates, 1024);
    k_lstm<<<(BB*EHID+255)/256, 256, 0, stream>>>(gates, cD, hB, EHID);
  }

  // ---- decoder init ----
  k_concat<<<(BB*DH+255)/256, 256, 0, stream>>>(hB, a_z, hA);
  k_zero_f<<<(BB*DH+255)/256, 256, 0, stream>>>(cD, BB*DH);
  k_copy_f<<<(BB*2+255)/256, 256, 0, stream>>>(a_traj + (size_t)7*BB*2, traj, BB*2);

  float* hcur = hA;
  float* hoth = hB;
  for (int i = 0; i < PRED; ++i){
    k_embed<<<BB, 64, 0, stream>>>(traj, a_Wemb, a_bemb, inp);
    if (i == 4){
      k_sg_emb<<<BB, 64, 0, stream>>>(hcur, a_Wne, a_bne, a_Watt, sself_d, sother_d);
      k_sg_edgecol<<<NG, NN, 0, stream>>>(sself_d, sother_d, a_batt, edge_d);
      k_sg_sym<<<(NG*NN*NN+255)/256, 256, 0, stream>>>(edge_d, esym_d);
      k_sg_dsum<<<(NG*NN+255)/256, 256, 0, stream>>>(esym_d, darr_d);
      k_sg_lsym<<<(NG*NN*NN+255)/256, 256, 0, stream>>>(esym_d, darr_d, Lpack);
      k_sg_eigen<<<NG, 256, EIG_LDS, stream>>>(Lpack, darr_d, v1_d);
      k_sg_kmeans<<<NG, 256, 0, stream>>>(darr_d, v1_d, labels);
      k_sg_alpha<<<NG, NN, 0, stream>>>(esym_d, labels, Smat);
      k_sg_feat<<<BB, DH, 0, stream>>>(Smat, hcur, hoth);
      float* tmp = hcur; hcur = hoth; hoth = tmp;
    }
    k_gates<<<dim3((4*DH)/64, BB/64), 256, 0, stream>>>(inp, a_Wihd, 64, hcur, a_Whhd, DH,
                                                        a_bihd, a_bhhd, gates, 4*DH);
    k_lstm<<<(BB*DH+255)/256, 256, 0, stream>>>(gates, cD, hcur, DH);
    k_outproj<<<BB, 64, 0, stream>>>(hcur, a_Wout, a_bout, traj, d_out, i, flag);
  }
}

// Round 9
// 3497.210 us; speedup vs baseline: 4.0649x; 1.5538x over previous
//
#include <hip/hip_runtime.h>
#include <hip/hip_bf16.h>

typedef __hip_bfloat16 bf16;

#define NN 192      // nodes per group
#define NG 8        // groups
#define BB 1536     // batch
#define EHID 256
#define DH 320      // decoder hidden
#define PRED 12
#define TRI ((NN*(NN+1))/2)   // 18528 packed lower-triangle elements

__device__ __forceinline__ float waveSum(float v){
#pragma unroll
  for (int o = 32; o > 0; o >>= 1) v += __shfl_down(v, o);
  return v;
}
__device__ __forceinline__ double waveSumD(double v){
#pragma unroll
  for (int o = 32; o > 0; o >>= 1) v += __shfl_down(v, o);
  return v;
}

__device__ __forceinline__ double blockSumD(double v, double* red){
  int lane = threadIdx.x & 63, wid = threadIdx.x >> 6, nw = (int)blockDim.x >> 6;
  double s = waveSumD(v);
  __syncthreads();
  if (lane == 0) red[wid] = s;
  __syncthreads();
  if (wid == 0){
    double t = (lane < nw) ? red[lane] : 0.0;
    t = waveSumD(t);
    if (lane == 0) red[0] = t;
  }
  __syncthreads();
  return red[0];
}

// ---------------- dtype probe + conversion ----------------

__global__ void k_zero_int(int* __restrict__ p, int n){
  int i = blockIdx.x*blockDim.x + threadIdx.x;
  if (i < n) p[i] = 0;
}
__global__ void k_zero_f(float* __restrict__ p, int n){
  int i = blockIdx.x*blockDim.x + threadIdx.x;
  if (i < n) p[i] = 0.f;
}

__global__ void k_probe(const unsigned short* __restrict__ src, int n, int* __restrict__ cnt){
  int tid = blockIdx.x*blockDim.x + threadIdx.x;
  int stride = gridDim.x*blockDim.x;
  int bad = 0;
  for (int j = tid; j < n; j += stride){
    float v = __uint_as_float(((unsigned int)src[j]) << 16);
    if (!(fabsf(v) < 100.f)) bad++;
  }
#pragma unroll
  for (int o = 32; o > 0; o >>= 1) bad += __shfl_down(bad, o);
  if ((threadIdx.x & 63) == 0 && bad > 0) atomicAdd(cnt, bad);
}
__global__ void k_flag(const int* __restrict__ cnt, int* __restrict__ flag){
  *flag = (*cnt > 4096) ? 1 : 0;        // 1 = inputs are fp32, 0 = bf16
}

struct CvtArgs {
  const void* src[20];
  float*      dst[20];
  int         n[20];
};

__global__ void k_convert(CvtArgs a, const int* __restrict__ flag){
  int id = blockIdx.y;
  int n = a.n[id];
  float* d = a.dst[id];
  int t = blockIdx.x*blockDim.x + threadIdx.x;
  int stride = gridDim.x*blockDim.x;
  if (*flag == 0){
    const bf16* s = (const bf16*)a.src[id];
    for (int j = t; j < n; j += stride) d[j] = __bfloat162float(s[j]);
  } else {
    const float* s = (const float*)a.src[id];
    for (int j = t; j < n; j += stride) d[j] = s[j];
  }
}

// ---------------- elementwise / small kernels ----------------

__global__ void k_embed(const float* __restrict__ in, const float* __restrict__ W,
                        const float* __restrict__ b, float* __restrict__ out){
  int r = blockIdx.x, e = threadIdx.x;
  float x = in[r*2], y = in[r*2+1];
  float v = W[e*2]*x + W[e*2+1]*y + b[e];
  out[r*64+e] = v > 0.f ? v : 0.f;
}

__global__ void k_concat(const float* __restrict__ henc, const float* __restrict__ z,
                         float* __restrict__ h){
  int idx = blockIdx.x*blockDim.x + threadIdx.x;
  if (idx >= BB*DH) return;
  int b = idx / DH, j = idx - b*DH;
  h[idx] = (j < EHID) ? henc[b*EHID + j] : z[(b/NN)*64 + (j - EHID)];
}

__global__ void k_copy_f(const float* __restrict__ in, float* __restrict__ dst, int n){
  int i = blockIdx.x*blockDim.x + threadIdx.x;
  if (i < n) dst[i] = in[i];
}

// gates = A1@W1^T + A2@W2^T + b1 + b2 ; M=1536, N,K multiples of 32/64
__global__ __launch_bounds__(256) void k_gates(
    const float* __restrict__ A1, const float* __restrict__ W1, int K1,
    const float* __restrict__ A2, const float* __restrict__ W2, int K2,
    const float* __restrict__ b1, const float* __restrict__ b2,
    float* __restrict__ C, int N){
  __shared__ __align__(16) float As[32][68];
  __shared__ __align__(16) float Ws[32][68];
  int tid = threadIdx.x;
  int tx = tid & 15, ty = tid >> 4;
  int n0 = blockIdx.x * 64, m0 = blockIdx.y * 64;
  float acc[4][4] = {};
  for (int ph = 0; ph < 2; ++ph){
    const float* A = ph ? A2 : A1;
    const float* W = ph ? W2 : W1;
    int K = ph ? K2 : K1;
    for (int k0 = 0; k0 < K; k0 += 32){
      {
        int am = tid >> 2, ak = (tid & 3) * 8;
        const float* srcA = A + (size_t)(m0+am)*K + k0 + ak;
        float4 f0 = *(const float4*)(srcA);
        float4 f1 = *(const float4*)(srcA+4);
        As[ak+0][am]=f0.x; As[ak+1][am]=f0.y; As[ak+2][am]=f0.z; As[ak+3][am]=f0.w;
        As[ak+4][am]=f1.x; As[ak+5][am]=f1.y; As[ak+6][am]=f1.z; As[ak+7][am]=f1.w;
        const float* srcW = W + (size_t)(n0+am)*K + k0 + ak;
        float4 w0 = *(const float4*)(srcW);
        float4 w1 = *(const float4*)(srcW+4);
        Ws[ak+0][am]=w0.x; Ws[ak+1][am]=w0.y; Ws[ak+2][am]=w0.z; Ws[ak+3][am]=w0.w;
        Ws[ak+4][am]=w1.x; Ws[ak+5][am]=w1.y; Ws[ak+6][am]=w1.z; Ws[ak+7][am]=w1.w;
      }
      __syncthreads();
#pragma unroll
      for (int k = 0; k < 32; ++k){
        float4 a0 = *(const float4*)&As[k][ty*4];
        float4 b0 = *(const float4*)&Ws[k][tx*4];
        float av[4] = {a0.x, a0.y, a0.z, a0.w};
        float bv[4] = {b0.x, b0.y, b0.z, b0.w};
#pragma unroll
        for (int i = 0; i < 4; ++i)
#pragma unroll
          for (int j = 0; j < 4; ++j)
            acc[i][j] += av[i]*bv[j];
      }
      __syncthreads();
    }
  }
  float bs[4];
#pragma unroll
  for (int j = 0; j < 4; ++j){
    int col = n0 + tx*4 + j;
    bs[j] = b1[col] + b2[col];
  }
#pragma unroll
  for (int i = 0; i < 4; ++i){
    int row = m0 + ty*4 + i;
    float4 v;
    v.x = acc[i][0] + bs[0]; v.y = acc[i][1] + bs[1];
    v.z = acc[i][2] + bs[2]; v.w = acc[i][3] + bs[3];
    *(float4*)&C[(size_t)row*N + n0 + tx*4] = v;
  }
}

__global__ void k_lstm(const float* __restrict__ gates, float* __restrict__ c,
                       float* __restrict__ h, int H){
  int idx = blockIdx.x*blockDim.x + threadIdx.x;
  if (idx >= BB*H) return;
  int b = idx / H, j = idx - b*H;
  const float* g = gates + (size_t)b*4*H;
  float gi = g[j], gf = g[H+j], gg = g[2*H+j], go = g[3*H+j];
  float si = 1.f/(1.f+expf(-gi));
  float sf = 1.f/(1.f+expf(-gf));
  float so = 1.f/(1.f+expf(-go));
  float cc = sf*c[idx] + si*tanhf(gg);
  c[idx] = cc;
  h[idx] = so*tanhf(cc);
}

// h(1536x320) -> traj(1536x2) fp32 + output slice `step` (fp32 or bf16 per flag)
__global__ void k_outproj(const float* __restrict__ h, const float* __restrict__ W,
                          const float* __restrict__ bo, float* __restrict__ traj,
                          void* __restrict__ outbase, int step, const int* __restrict__ flag){
  int b = blockIdx.x, lane = threadIdx.x;
  const float* hb = h + (size_t)b*DH;
  float a0 = 0.f, a1 = 0.f;
  for (int k = lane; k < DH; k += 64){
    float hv = hb[k];
    a0 += hv*W[k];
    a1 += hv*W[DH+k];
  }
  a0 = waveSum(a0); a1 = waveSum(a1);
  if (lane == 0){
    a0 += bo[0]; a1 += bo[1];
    traj[b*2] = a0; traj[b*2+1] = a1;
    size_t idx = (size_t)step*BB*2 + (size_t)b*2;
    if (*flag == 0){
      bf16* o = (bf16*)outbase;
      o[idx] = __float2bfloat16(a0); o[idx+1] = __float2bfloat16(a1);
    } else {
      float* o = (float*)outbase;
      o[idx] = a0; o[idx+1] = a1;
    }
  }
}

// ---------------- signed-graph kernels (fp64 numeric path) ----------------

__global__ void k_sg_emb(const float* __restrict__ h, const float* __restrict__ Wne,
                         const float* __restrict__ bne, const float* __restrict__ Watt,
                         double* __restrict__ sself, double* __restrict__ sother){
  int node = blockIdx.x, e = threadIdx.x;
  const float* hb = h + (size_t)node*DH;
  double acc = (double)bne[e];
  for (int k = 0; k < DH; ++k) acc += (double)hb[k]*(double)Wne[e*DH+k];
  double po = acc * (double)Watt[e];       // a_other = W_att[0, :64]
  double ps = acc * (double)Watt[64+e];    // a_self  = W_att[0, 64:]
  po = waveSumD(po); ps = waveSumD(ps);
  if (e == 0){ sother[node] = po; sself[node] = ps; }
}

__global__ void k_sg_edgecol(const double* __restrict__ sself, const double* __restrict__ sother,
                             const float* __restrict__ batt, double* __restrict__ edge){
  int g = blockIdx.x, j = threadIdx.x;
  const double* ss = sself + g*NN;
  double bb = (double)batt[0];
  double sj = sother[g*NN + j];
  double m = -1e300;
  for (int i = 0; i < NN; ++i){
    double e = ss[i] + sj + bb; e = e > 0.0 ? e : 0.2*e;
    m = fmax(m, e);
  }
  double sum = 0.0;
  for (int i = 0; i < NN; ++i){
    double e = ss[i] + sj + bb; e = e > 0.0 ? e : 0.2*e;
    sum += exp(e - m);
  }
  double* E = edge + (size_t)g*NN*NN;
  for (int i = 0; i < NN; ++i){
    double e = ss[i] + sj + bb; e = e > 0.0 ? e : 0.2*e;
    E[i*NN + j] = exp(e - m)/sum;
  }
}

__global__ void k_sg_sym(const double* __restrict__ edge, double* __restrict__ esym){
  int idx = blockIdx.x*blockDim.x + threadIdx.x;
  if (idx >= NG*NN*NN) return;
  int g = idx / (NN*NN), r = idx - g*NN*NN;
  int i = r / NN, j = r - i*NN;
  const double* E = edge + (size_t)g*NN*NN;
  esym[idx] = (i <= j) ? E[i*NN + j] : E[j*NN + i];
}

__global__ void k_sg_dsum(const double* __restrict__ esym, double* __restrict__ darr){
  int i = blockIdx.x*blockDim.x + threadIdx.x;
  if (i >= NG*NN) return;
  int g = i / NN, li = i - g*NN;
  const double* E = esym + (size_t)g*NN*NN + (size_t)li*NN;
  double s = 0.0;
  for (int j = 0; j < NN; ++j) s += E[j];
  darr[i] = fmax(s, 1e-300);
}

// packed lower-triangle L_sym
__global__ void k_sg_lsym(const double* __restrict__ esym, const double* __restrict__ darr,
                          double* __restrict__ Lpack){
  int idx = blockIdx.x*blockDim.x + threadIdx.x;
  if (idx >= NG*NN*NN) return;
  int g = idx / (NN*NN), r = idx - g*NN*NN;
  int i = r / NN, j = r - i*NN;
  if (j > i) return;
  double w = esym[idx];
  double lij = (i == j) ? (darr[g*NN+i] - w) : (-w);
  Lpack[(size_t)g*TRI + i*(i+1)/2 + j] = lij / (sqrt(darr[g*NN+i])*sqrt(darr[g*NN+j]));
}

// LDS-RESIDENT packed-symmetric Householder tridiag, 1024 threads (16 waves):
// wave-per-row matvec/rank-2 with lane-split columns (uniform bounds, coalesced
// packed addresses). + Sturm bisection + inverse iteration + back-transform +
// Gram-Schmidt vs v0=sqrt(d). dynamic LDS = (TRI + 8*NN + 32)*8 = 160768 B.
__global__ __launch_bounds__(1024) void k_sg_eigen(const double* __restrict__ Lpack,
                                                   const double* __restrict__ darr,
                                                   double* __restrict__ v1out){
  extern __shared__ double lds[];
  double* tri   = lds;                 // TRI
  double* v     = lds + TRI;           // NN
  double* p     = v + NN;              // NN
  double* dd    = p + NN;              // NN
  double* ee    = dd + NN;             // NN
  double* yv    = ee + NN;             // NN
  double* lu_d  = yv + NN;             // NN
  double* lu_du = lu_d + NN;           // NN
  double* lu_du2= lu_du + NN;          // NN
  double* redA  = lu_du2 + NN;         // 16
  double* redB  = redA + 16;           // 16
  double* lu_dl = v;                   // alias: v dead in LU phase
  int*    lu_piv= (int*)p;             // alias: p dead in LU phase

  int g = blockIdx.x, tid = threadIdx.x;
  int lane = tid & 63, wid = tid >> 6;  // 16 waves

  const double* src = Lpack + (size_t)g*TRI;
  for (int t = tid; t < TRI; t += 1024) tri[t] = src[t];
  __syncthreads();

  // ---- tridiagonalization (all in LDS) ----
  for (int k = 0; k < NN-2; ++k){
    int m = NN-1-k;                      // trailing rows i = k+1 .. NN-1
    // phase A: v = column k, sigma = sum_{i>k+1} v_i^2
    double part = 0.0;
    if (tid < m){
      int i = k+1+tid;
      double x = tri[i*(i+1)/2 + k];
      v[i] = x;
      if (i > k+1) part = x*x;
    }
    part = waveSumD(part);
    if (lane == 0) redA[wid] = part;
    __syncthreads();                                   // B1
    double sigma = 0.0;
#pragma unroll
    for (int w = 0; w < 16; ++w) sigma += redA[w];
    double alpha = v[k+1];
    double beta, tau, scale;
    if (sigma <= 1e-280){ tau = 0.0; beta = alpha; scale = 0.0; }
    else {
      beta = -copysign(sqrt(alpha*alpha + sigma), alpha);
      tau = (beta - alpha)/beta;
      scale = 1.0/(alpha - beta);
    }
    if (tid == 0){
      int dk = k*(k+1)/2 + k;
      dd[k] = tri[dk]; ee[k] = beta;
      tri[dk] = tau;                                   // stash tau (diag slot dead)
    }
    if (tau != 0.0){                                   // block-uniform branch
      if (tid < m-1){                                  // store scaled u into col k
        int i = k+2+tid;
        tri[i*(i+1)/2 + k] = v[i]*scale;               // disjoint from matvec reads
      }
      // matvec: wave-per-row, lanes split columns (uniform bounds)
      for (int r = wid; r < m; r += 16){
        int i = k+1+r, bi = (i*(i+1))>>1;
        double s = 0.0;
        for (int j = k+2+lane; j < NN; j += 64){
          double Aij = (j <= i) ? tri[bi + j] : tri[((j*(j+1))>>1) + i];
          s += Aij * v[j];
        }
        s = waveSumD(s);
        if (lane == 0) p[i] = tau*(tri[bi + k+1] + scale*s);
      }
      __syncthreads();                                 // B2: p complete
      double pk1 = p[k+1];                             // snapshot (race-free)
      double pp = 0.0;
      if (tid < m-1){ int i = k+2+tid; pp = v[i]*scale*p[i]; }
      pp = waveSumD(pp);
      if (lane == 0) redB[wid] = pp;
      __syncthreads();                                 // B3
      double vtp = pk1;
#pragma unroll
      for (int w = 0; w < 16; ++w) vtp += redB[w];
      double Kc = 0.5*tau*vtp;
      if (tid == 0) p[k+1] -= Kc;
      if (tid < m-1){ int i = k+2+tid; p[i] -= Kc*v[i]*scale; }
      __syncthreads();                                 // B4: w complete
      // rank-2: wave-per-row (balanced pairing r <-> m-1-r), lanes split cols
      int half = (m+1) >> 1;
      for (int r = wid; r < half; r += 16){
        {
          int i = k+1+r, bi = (i*(i+1))>>1;
          double ui = (r == 0) ? 1.0 : v[i]*scale;
          double wi = p[i];
          for (int j = k+1+lane; j <= i; j += 64){
            double uj = (j == k+1) ? 1.0 : v[j]*scale;
            tri[bi+j] -= ui*p[j] + wi*uj;
          }
        }
        int r2 = m-1-r;
        if (r2 != r){
          int i = k+1+r2, bi = (i*(i+1))>>1;
          double ui = (r2 == 0) ? 1.0 : v[i]*scale;
          double wi = p[i];
          for (int j = k+1+lane; j <= i; j += 64){
            double uj = (j == k+1) ? 1.0 : v[j]*scale;
            tri[bi+j] -= ui*p[j] + wi*uj;
          }
        }
      }
      __syncthreads();                                 // B5
    } else {
      __syncthreads();                                 // uniform barrier count
    }
  }
  if (tid == 0){
    dd[NN-2] = tri[(NN-2)*(NN-1)/2 + (NN-2)];
    ee[NN-2] = tri[(NN-1)*NN/2 + (NN-2)];
    dd[NN-1] = tri[(NN-1)*NN/2 + (NN-1)];
  }
  __syncthreads();

  // ---- bisection (wave 0) + serial LU/inverse-iteration (lane 0) ----
  if (wid == 0){
    double mn = 1e300, mx = -1e300;
    for (int i = lane; i < NN; i += 64){
      double r = (i > 0 ? fabs(ee[i-1]) : 0.0) + (i < NN-1 ? fabs(ee[i]) : 0.0);
      mn = fmin(mn, dd[i]-r); mx = fmax(mx, dd[i]+r);
    }
#pragma unroll
    for (int o = 32; o > 0; o >>= 1){
      mn = fmin(mn, __shfl_down(mn, o));
      mx = fmax(mx, __shfl_down(mx, o));
    }
    mn = __shfl(mn, 0); mx = __shfl(mx, 0);
    double lo = mn - 1e-8 - 1e-9*fabs(mn);
    double hi = mx + 1e-8 + 1e-9*fabs(mx);
    for (int it = 0; it < 10; ++it){
      double lam = lo + (hi-lo)*((double)(lane+1)/65.0);
      int cnt = 0;
      double q = dd[0] - lam;
      if (q < 0.0) cnt++;
      for (int i2 = 1; i2 < NN; ++i2){
        double den = q;
        if (fabs(den) < 1e-280) den = (den < 0.0) ? -1e-280 : 1e-280;
        q = dd[i2] - lam - ee[i2-1]*ee[i2-1]/den;
        if (q < 0.0) cnt++;
      }
      unsigned long long bal = __ballot(cnt >= 2);
      if (bal == 0ull){
        lo = lo + (hi-lo)*(64.0/65.0);
      } else {
        int j0 = __ffsll(bal) - 1;
        double nl = lo + (hi-lo)*((double)j0/65.0);
        double nh = lo + (hi-lo)*((double)(j0+1)/65.0);
        lo = nl; hi = nh;
      }
    }
    double lam1 = 0.5*(lo+hi);

    if (lane == 0){
      for (int i = 0; i < NN; ++i) lu_d[i] = dd[i] - lam1;
      for (int i = 0; i < NN-1; ++i){ lu_dl[i] = ee[i]; lu_du[i] = ee[i]; }
      for (int i = 0; i < NN-2; ++i) lu_du2[i] = 0.0;
      for (int i = 0; i < NN-1; ++i){
        if (fabs(lu_d[i]) >= fabs(lu_dl[i])){
          double di = lu_d[i];
          if (fabs(di) < 1e-30){ di = (di < 0.0) ? -1e-30 : 1e-30; lu_d[i] = di; }
          double fact = lu_dl[i]/di;
          lu_dl[i] = fact;
          lu_d[i+1] -= fact*lu_du[i];
          lu_piv[i] = 0;
        } else {
          double fact = lu_d[i]/lu_dl[i];
          lu_d[i] = lu_dl[i];
          double tmp = lu_d[i+1];
          lu_d[i+1] = lu_du[i] - fact*tmp;
          if (i < NN-2){ lu_du2[i] = lu_du[i+1]; lu_du[i+1] = -fact*lu_du[i+1]; }
          lu_du[i] = tmp;
          lu_dl[i] = fact;
          lu_piv[i] = 1;
        }
      }
      if (fabs(lu_d[NN-1]) < 1e-30)
        lu_d[NN-1] = (lu_d[NN-1] < 0.0) ? -1e-30 : 1e-30;
      for (int i = 0; i < NN; ++i) yv[i] = 1.0 + 0.001*(double)((i*37)%29);
      for (int round = 0; round < 2; ++round){
        for (int i = 0; i < NN-1; ++i){
          if (lu_piv[i] == 0){
            yv[i+1] -= lu_dl[i]*yv[i];
          } else {
            double t = yv[i]; yv[i] = yv[i+1]; yv[i+1] = t - lu_dl[i]*yv[i];
          }
        }
        double mx1 = 0.0;
        for (int i = 0; i < NN; ++i) mx1 = fmax(mx1, fabs(yv[i]));
        double inv1 = (mx1 > 0.0 && isfinite(mx1)) ? 1.0/mx1 : 1.0;
        for (int i = 0; i < NN; ++i) yv[i] *= inv1;
        yv[NN-1] = yv[NN-1]/lu_d[NN-1];
        yv[NN-2] = (yv[NN-2] - lu_du[NN-2]*yv[NN-1])/lu_d[NN-2];
        for (int i = NN-3; i >= 0; --i)
          yv[i] = (yv[i] - lu_du[i]*yv[i+1] - lu_du2[i]*yv[i+2])/lu_d[i];
        double mxv = 0.0;
        for (int i = 0; i < NN; ++i) mxv = fmax(mxv, fabs(yv[i]));
        double inv = (mxv > 0.0 && isfinite(mxv)) ? 1.0/mxv : 1.0;
        for (int i = 0; i < NN; ++i){
          double val = yv[i]*inv;
          if (!isfinite(val)) val = 0.0;
          yv[i] = val;
        }
      }
    }
  }
  __syncthreads();                                     // yv ready

  // ---- back-transform: y <- H_0 ... H_{n-3} y (vectors in LDS tri cols) ----
  for (int k = NN-3; k >= 0; --k){
    double tau = tri[k*(k+1)/2 + k];
    if (tau != 0.0){                                   // block-uniform
      int i = k+1+tid;
      double ui = 0.0, part = 0.0;
      if (tid < NN-1-k){
        ui = (tid == 0) ? 1.0 : tri[i*(i+1)/2 + k];
        part = ui*yv[i];
      }
      part = waveSumD(part);
      if (lane == 0) redA[wid] = part;
      __syncthreads();
      double dot = 0.0;
#pragma unroll
      for (int w = 0; w < 16; ++w) dot += redA[w];
      double s = tau*dot;
      if (tid < NN-1-k) yv[i] -= s*ui;
    }
    __syncthreads();
  }

  // ---- Gram-Schmidt against v0 = sqrt(d) + normalize ----
  {
    double pd = 0.0, pn2 = 0.0;
    if (tid < NN){
      double sd = sqrt(darr[g*NN + tid]);
      pd = sd*yv[tid];
      pn2 = darr[g*NN + tid];
    }
    pd = waveSumD(pd); pn2 = waveSumD(pn2);
    if (lane == 0){ redA[wid] = pd; redB[wid] = pn2; }
    __syncthreads();
    double dot = 0.0, n2 = 0.0;
#pragma unroll
    for (int w = 0; w < 16; ++w){ dot += redA[w]; n2 += redB[w]; }
    double coef = dot/fmax(n2, 1e-300);
    if (tid < NN) yv[tid] -= coef*sqrt(darr[g*NN + tid]);
    __syncthreads();
    double pn = 0.0;
    if (tid < NN) pn = yv[tid]*yv[tid];
    pn = waveSumD(pn);
    if (lane == 0) redA[wid] = pn;
    __syncthreads();
    double s2 = 0.0;
#pragma unroll
    for (int w = 0; w < 16; ++w) s2 += redA[w];
    double nrm = sqrt(s2);
    double inv = (nrm > 0.0 && isfinite(nrm)) ? 1.0/nrm : 0.0;
    if (tid < NN){
      double val = yv[tid]*inv;
      if (!isfinite(val)) val = 0.0;
      v1out[g*NN + tid] = val;
    }
  }
}

// kmeans on row-normalized [sqrt(d)/||.||, v1]  (fp64)
__global__ __launch_bounds__(256) void k_sg_kmeans(const double* __restrict__ darr,
                                                   const double* __restrict__ v1,
                                                   int* __restrict__ labels){
  __shared__ double px[NN], py[NN], cx[96], cy[96];
  __shared__ int lab[NN];
  __shared__ double red[16];
  int g = blockIdx.x, tid = threadIdx.x;
  double part = 0.0;
  for (int i = tid; i < NN; i += 256) part += darr[g*NN + i];
  double sumd = blockSumD(part, red);
  double invn = 1.0/sqrt(fmax(sumd, 1e-300));
  for (int i = tid; i < NN; i += 256){
    double h0 = sqrt(darr[g*NN + i])*invn;
    double h1 = v1[g*NN + i];
    double rn = sqrt(h0*h0 + h1*h1);
    double ax = h0/rn, ay = h1/rn;
    if (!isfinite(ax)) ax = 0.0;
    if (!isfinite(ay)) ay = 0.0;
    px[i] = ax; py[i] = ay;
  }
  __syncthreads();
  if (tid < 96){ cx[tid] = px[tid]; cy[tid] = py[tid]; }
  __syncthreads();
  for (int it = 0; it <= 10; ++it){
    if (tid < NN){
      double bx = px[tid], by = py[tid];
      double best = 1e300; int bi = 0;
      for (int a = 0; a < 96; ++a){
        double dx = bx - cx[a], dy = by - cy[a];
        double d2 = dx*dx + dy*dy;
        if (d2 < best){ best = d2; bi = a; }
      }
      lab[tid] = bi;
    }
    __syncthreads();
    if (it == 10) break;
    if (tid < 96){
      int c = 0; double sx = 0.0, sy = 0.0;
      for (int i = 0; i < NN; ++i){
        if (lab[i] == tid){ c++; sx += px[i]; sy += py[i]; }
      }
      if (c > 0){ cx[tid] = sx/(double)c; cy[tid] = sy/(double)c; }
      else      { cx[tid] = px[tid];      cy[tid] = py[tid]; }
    }
    __syncthreads();
  }
  if (tid < NN) labels[g*NN + tid] = lab[tid];
}

// S = pos_alpha + neg_alpha (fp64 in, fp32 out)
__global__ void k_sg_alpha(const double* __restrict__ esym, const int* __restrict__ labels,
                           float* __restrict__ S){
  __shared__ int lbs[NN];
  int g = blockIdx.x, j = threadIdx.x;
  if (j < NN) lbs[j] = labels[g*NN + j];
  __syncthreads();
  const double* E = esym + (size_t)g*NN*NN;
  const double NEG = -100000000.0;
  int lj = lbs[j];
  double mp = -1e300, mn = -1e300;
  for (int i = 0; i < NN; ++i){
    double w = E[i*NN + j];
    bool sm = (lbs[i] == lj);
    double vp = sm ? w : w*NEG; vp = vp > 0.0 ? vp : 0.2*vp;
    double vn = sm ? w*NEG : w; vn = vn > 0.0 ? vn : 0.2*vn;
    mp = fmax(mp, vp); mn = fmax(mn, vn);
  }
  double sp = 0.0, sn = 0.0;
  for (int i = 0; i < NN; ++i){
    double w = E[i*NN + j];
    bool sm = (lbs[i] == lj);
    double vp = sm ? w : w*NEG; vp = vp > 0.0 ? vp : 0.2*vp;
    double vn = sm ? w*NEG : w; vn = vn > 0.0 ? vn : 0.2*vn;
    sp += exp(vp - mp); sn += exp(vn - mn);
  }
  float* So = S + (size_t)g*NN*NN;
  for (int i = 0; i < NN; ++i){
    double w = E[i*NN + j];
    bool sm = (lbs[i] == lj);
    double vp = sm ? w : w*NEG; vp = vp > 0.0 ? vp : 0.2*vp;
    double vn = sm ? w*NEG : w; vn = vn > 0.0 ? vn : 0.2*vn;
    So[i*NN + j] = (float)(exp(vp - mp)/sp + exp(vn - mn)/sn);
  }
}

// h_out[i,:] = sum_j S[i,j] * relu(h_in[j,:]) per group
__global__ __launch_bounds__(320) void k_sg_feat(const float* __restrict__ S,
                                                 const float* __restrict__ hin,
                                                 float* __restrict__ hout){
  int r = blockIdx.x;
  int g = r / NN, li = r - g*NN;
  int dh = threadIdx.x;
  const float* Srow = S + (size_t)g*NN*NN + (size_t)li*NN;
  const float* hb = hin + (size_t)g*NN*DH;
  float acc = 0.f;
  for (int j = 0; j < NN; ++j){
    float w = Srow[j];
    float x = hb[(size_t)j*DH + dh];
    acc += w*(x > 0.f ? x : 0.f);
  }
  hout[(size_t)r*DH + dh] = acc;
}

// ---------------- host ----------------

extern "C" void kernel_launch(void* const* d_in, const int* in_sizes, int n_in,
                              void* d_out, int out_size, void* d_ws, size_t ws_size,
                              hipStream_t stream){
  (void)n_in; (void)out_size; (void)ws_size;

  // ---- workspace layout (float offsets) ----
  float* ws = (float*)d_ws;
  float* inp   = ws;                       // 98304
  float* gates = ws + 98304;               // 1966080
  float* hA    = ws + 2064384;             // 491520
  float* hB    = ws + 2555904;             // 491520
  float* cD    = ws + 3047424;             // 491520
  float* traj  = ws + 3538944;             // 3072
  double* sself_d  = (double*)(ws + 3542016);  // 3072 f
  double* sother_d = (double*)(ws + 3545088);  // 3072 f
  double* darr_d   = (double*)(ws + 3548160);  // 3072 f
  double* v1_d     = (double*)(ws + 3551232);  // 3072 f
  int*    labels   = (int*)(ws + 3554304);     // 1536
  // fp64 graph matrices overlay the (dead) gates buffer:
  double* edge_d = (double*)gates;             // 589824 f
  double* esym_d = (double*)(gates + 589824);  // 589824 f
  double* Lpack  = (double*)(gates + 1179648); // packed: NG*TRI dbl = 296448 f
  float*  Smat   = gates;                      // fp32 S reuses edge_d space (dead by then)
  // fp32 parameter arena:
  float* a_traj = ws + 3555840;            // 61440
  float* a_z    = ws + 3617280;            // 512
  float* a_Wemb = ws + 3617792;            // 128
  float* a_bemb = ws + 3617920;            // 64
  float* a_Wihe = ws + 3617984;            // 65536
  float* a_Whhe = ws + 3683520;            // 262144
  float* a_bihe = ws + 3945664;            // 1024
  float* a_bhhe = ws + 3946688;            // 1024
  float* a_Wihd = ws + 3947712;            // 81920
  float* a_Whhd = ws + 4029632;            // 409600
  float* a_bihd = ws + 4439232;            // 1280
  float* a_bhhd = ws + 4440512;            // 1280
  float* a_Wout = ws + 4441792;            // 640
  float* a_bout = ws + 4442432;            // 64
  float* a_Wne  = ws + 4442496;            // 20480
  float* a_bne  = ws + 4462976;            // 64
  float* a_Watt = ws + 4463040;            // 128
  float* a_batt = ws + 4463168;            // 64
  int* cnt  = (int*)(ws + 4463232);
  int* flag = (int*)(ws + 4463233);        // ~17.0 MiB total

  // allow >64KB dynamic LDS for the eigen kernel (idempotent, host-side)
  const int EIG_LDS = (int)((TRI + 8*NN + 32) * sizeof(double));   // 160768
  hipFuncSetAttribute((const void*)k_sg_eigen,
                      hipFuncAttributeMaxDynamicSharedMemorySize, EIG_LDS);

  // ---- dtype probe ----
  k_zero_int<<<1, 64, 0, stream>>>(cnt, 2);
  k_probe<<<256, 256, 0, stream>>>((const unsigned short*)d_in[1], in_sizes[1], cnt);
  k_flag<<<1, 1, 0, stream>>>(cnt, flag);

  // ---- convert all float inputs to fp32 (enc h/c straight into hB/cD) ----
  CvtArgs ca;
  float* dsts[20] = { a_traj, hB, cD, a_z, a_Wemb, a_bemb, a_Wihe, a_Whhe, a_bihe,
                      a_bhhe, a_Wihd, a_Whhd, a_bihd, a_bhhd, a_Wout, a_bout,
                      a_Wne, a_bne, a_Watt, a_batt };
  for (int i = 0; i < 20; ++i){
    ca.src[i] = d_in[i];
    ca.dst[i] = dsts[i];
    ca.n[i]   = in_sizes[i];
  }
  k_convert<<<dim3(512, 20), 256, 0, stream>>>(ca, flag);

  // ---- encoder LSTM, 8 steps ----
  for (int t = 0; t < 8; ++t){
    k_embed<<<BB, 64, 0, stream>>>(a_traj + (size_t)t*BB*2, a_Wemb, a_bemb, inp);
    k_gates<<<dim3(1024/64, BB/64), 256, 0, stream>>>(inp, a_Wihe, 64, hB, a_Whhe, EHID,
                                                      a_bihe, a_bhhe, gates, 1024);
    k_lstm<<<(BB*EHID+255)/256, 256, 0, stream>>>(gates, cD, hB, EHID);
  }

  // ---- decoder init ----
  k_concat<<<(BB*DH+255)/256, 256, 0, stream>>>(hB, a_z, hA);
  k_zero_f<<<(BB*DH+255)/256, 256, 0, stream>>>(cD, BB*DH);
  k_copy_f<<<(BB*2+255)/256, 256, 0, stream>>>(a_traj + (size_t)7*BB*2, traj, BB*2);

  float* hcur = hA;
  float* hoth = hB;
  for (int i = 0; i < PRED; ++i){
    k_embed<<<BB, 64, 0, stream>>>(traj, a_Wemb, a_bemb, inp);
    if (i == 4){
      k_sg_emb<<<BB, 64, 0, stream>>>(hcur, a_Wne, a_bne, a_Watt, sself_d, sother_d);
      k_sg_edgecol<<<NG, NN, 0, stream>>>(sself_d, sother_d, a_batt, edge_d);
      k_sg_sym<<<(NG*NN*NN+255)/256, 256, 0, stream>>>(edge_d, esym_d);
      k_sg_dsum<<<(NG*NN+255)/256, 256, 0, stream>>>(esym_d, darr_d);
      k_sg_lsym<<<(NG*NN*NN+255)/256, 256, 0, stream>>>(esym_d, darr_d, Lpack);
      k_sg_eigen<<<NG, 1024, EIG_LDS, stream>>>(Lpack, darr_d, v1_d);
      k_sg_kmeans<<<NG, 256, 0, stream>>>(darr_d, v1_d, labels);
      k_sg_alpha<<<NG, NN, 0, stream>>>(esym_d, labels, Smat);
      k_sg_feat<<<BB, DH, 0, stream>>>(Smat, hcur, hoth);
      float* tmp = hcur; hcur = hoth; hoth = tmp;
    }
    k_gates<<<dim3((4*DH)/64, BB/64), 256, 0, stream>>>(inp, a_Wihd, 64, hcur, a_Whhd, DH,
                                                        a_bihd, a_bhhd, gates, 4*DH);
    k_lstm<<<(BB*DH+255)/256, 256, 0, stream>>>(gates, cD, hcur, DH);
    k_outproj<<<BB, 64, 0, stream>>>(hcur, a_Wout, a_bout, traj, d_out, i, flag);
  }
}